// Round 1
// baseline (1482.254 us; speedup 1.0000x reference)
//
#include <hip/hip_runtime.h>
#include <hip/hip_bf16.h>
#include <math.h>

#define B_   16
#define L_   2048
#define DIN  512
#define HID_ 512
#define H_   8
#define D_   64
#define U_   40
#define BH   (B_*H_)     // 128

// ---------------- generic f32 tiled GEMM: C(MxN) = A(MxK) @ B(KxN), row-major ----
template<int BM, int BN, int BK, int TM, int TN>
__global__ __launch_bounds__(256)
void gemm_f32(const float* __restrict__ A, const float* __restrict__ Bm,
              float* __restrict__ C, int M, int N, int K) {
  __shared__ float As[BK][BM + 4];
  __shared__ float Bs[BK][BN + 4];
  const int t = threadIdx.x;
  const int row0 = blockIdx.x * BM;
  const int col0 = blockIdx.y * BN;
  const int NTX = BN / TN;
  const int tx = t % NTX, ty = t / NTX;
  float acc[TM][TN];
  #pragma unroll
  for (int i = 0; i < TM; ++i)
    #pragma unroll
    for (int j = 0; j < TN; ++j) acc[i][j] = 0.f;

  for (int k0 = 0; k0 < K; k0 += BK) {
    #pragma unroll
    for (int e = t * 4; e < BM * BK; e += 1024) {
      int r = e / BK, kk = e % BK;   // kk multiple of 4
      float4 v = *reinterpret_cast<const float4*>(&A[(size_t)(row0 + r) * K + k0 + kk]);
      As[kk + 0][r] = v.x; As[kk + 1][r] = v.y; As[kk + 2][r] = v.z; As[kk + 3][r] = v.w;
    }
    #pragma unroll
    for (int e = t * 4; e < BK * BN; e += 1024) {
      int kk = e / BN, c = e % BN;   // c multiple of 4
      *reinterpret_cast<float4*>(&Bs[kk][c]) =
          *reinterpret_cast<const float4*>(&Bm[(size_t)(k0 + kk) * N + col0 + c]);
    }
    __syncthreads();
    #pragma unroll
    for (int k = 0; k < BK; ++k) {
      float a[TM], b[TN];
      #pragma unroll
      for (int i = 0; i < TM; ++i) a[i] = As[k][ty * TM + i];
      #pragma unroll
      for (int j = 0; j < TN; ++j) b[j] = Bs[k][tx * TN + j];
      #pragma unroll
      for (int i = 0; i < TM; ++i)
        #pragma unroll
        for (int j = 0; j < TN; ++j) acc[i][j] += a[i] * b[j];
    }
    __syncthreads();
  }
  #pragma unroll
  for (int i = 0; i < TM; ++i)
    #pragma unroll
    for (int j = 0; j < TN; j += 4) {
      float4 o = make_float4(acc[i][j], acc[i][j+1], acc[i][j+2], acc[i][j+3]);
      *reinterpret_cast<float4*>(&C[(size_t)(row0 + ty * TM + i) * N + col0 + tx * TN + j]) = o;
    }
}

// ---------------- dot[bh,l] = sum_d q[bh,l,d]*k[bh,indx[l],d]; M = dot - dot*(U/L) ----
__global__ __launch_bounds__(256)
void dot_kernel(const float* __restrict__ qp, const float* __restrict__ kp,
                const int* __restrict__ indx, float* __restrict__ dotM) {
  int tid = blockIdx.x * 256 + threadIdx.x;
  int w = tid >> 6;       // dot index in [0, BH*L)
  int lane = tid & 63;
  int bh = w >> 11;       // / 2048
  int l = w & 2047;
  size_t boff = (size_t)bh * (L_ * D_);
  float q = qp[boff + (size_t)l * D_ + lane];
  int ls = indx[l];
  float k = kp[boff + (size_t)ls * D_ + lane];
  float p = q * k;
  #pragma unroll
  for (int off = 32; off >= 1; off >>= 1) p += __shfl_xor(p, off, 64);
  if (lane == 0) {
    const float cUL = 40.0f / 2048.0f;
    dotM[(size_t)bh * L_ + l] = p - p * cUL;
  }
}

// ---------------- per-(b,h) top-40 by value, ties -> lower index --------------------
__global__ __launch_bounds__(256)
void topk_kernel(const float* __restrict__ dotM, int* __restrict__ mtop) {
  __shared__ float vals[L_];
  __shared__ float rv[256];
  __shared__ int   ri[256];
  int bh = blockIdx.x, t = threadIdx.x;
  const float* row = dotM + (size_t)bh * L_;
  for (int i = t; i < L_; i += 256) vals[i] = row[i];
  __syncthreads();
  for (int u = 0; u < U_; ++u) {
    float bv = -INFINITY; int bi = 0x7fffffff;
    for (int i = t; i < L_; i += 256) {
      float v = vals[i];
      if (v > bv || (v == bv && i < bi)) { bv = v; bi = i; }
    }
    rv[t] = bv; ri[t] = bi;
    __syncthreads();
    for (int s = 128; s > 0; s >>= 1) {
      if (t < s) {
        float v2 = rv[t + s]; int i2 = ri[t + s];
        if (v2 > rv[t] || (v2 == rv[t] && i2 < ri[t])) { rv[t] = v2; ri[t] = i2; }
      }
      __syncthreads();
    }
    if (t == 0) { mtop[bh * U_ + u] = ri[0]; vals[ri[0]] = -INFINITY; }
    __syncthreads();
  }
}

// ---------------- fused masked-attention per (bh,u): flash-style online softmax -----
__global__ __launch_bounds__(256)
void attn_kernel(const float* __restrict__ qp, const float* __restrict__ kp,
                 const float* __restrict__ vp, const int* __restrict__ mtop,
                 float* __restrict__ upd) {
  __shared__ float lm[4], lssum[4];
  __shared__ float lacc[4][64];
  int blk = blockIdx.x;             // bh*U + u
  int t = threadIdx.x;
  int lane = t & 63, g = t >> 6;
  int bh = blk / U_;
  int m = mtop[blk];
  size_t boff = (size_t)bh * (L_ * D_);
  float qd = qp[boff + (size_t)m * D_ + lane];
  float mval = -INFINITY, ssum = 0.f, acc = 0.f;
  for (int l = g; l <= m; l += 4) {
    float kd = kp[boff + (size_t)l * D_ + lane];
    float p = qd * kd;
    #pragma unroll
    for (int off = 32; off >= 1; off >>= 1) p += __shfl_xor(p, off, 64);
    float s = p * 0.125f;
    float nm = fmaxf(mval, s);
    float sc = expf(mval - nm);    // 0 on first iteration (mval=-inf)
    float w  = expf(s - nm);
    ssum = ssum * sc + w;
    acc  = acc  * sc + w * vp[boff + (size_t)l * D_ + lane];
    mval = nm;
  }
  if (lane == 0) { lm[g] = mval; lssum[g] = ssum; }
  lacc[g][lane] = acc;
  __syncthreads();
  if (t < 64) {
    float M = fmaxf(fmaxf(lm[0], lm[1]), fmaxf(lm[2], lm[3]));
    float S = 0.f, A = 0.f;
    #pragma unroll
    for (int gg = 0; gg < 4; ++gg) {
      float e = expf(lm[gg] - M);   // 0 for empty waves (lm=-inf)
      S += lssum[gg] * e;
      A += lacc[gg][t] * e;
    }
    upd[(size_t)blk * 64 + t] = A / S;
  }
}

// ---------------- inclusive cumsum of v along l (per bh, per d) ---------------------
__global__ __launch_bounds__(256)
void cumsum_kernel(const float* __restrict__ vp, float* __restrict__ ctx) {
  __shared__ float segsum[4][64];
  int bh = blockIdx.x, t = threadIdx.x;
  int lane = t & 63, seg = t >> 6;
  size_t boff = (size_t)bh * (L_ * D_);
  const int SEG = L_ / 4;   // 512
  int l0 = seg * SEG;
  float s = 0.f;
  for (int l = l0; l < l0 + SEG; ++l) s += vp[boff + (size_t)l * D_ + lane];
  segsum[seg][lane] = s;
  __syncthreads();
  float run = 0.f;
  for (int ss = 0; ss < seg; ++ss) run += segsum[ss][lane];
  for (int l = l0; l < l0 + SEG; ++l) {
    run += vp[boff + (size_t)l * D_ + lane];
    ctx[boff + (size_t)l * D_ + lane] = run;
  }
}

// ---------------- scatter upd rows into ctx at m_top --------------------------------
__global__ __launch_bounds__(256)
void scatter_kernel(const float* __restrict__ upd, const int* __restrict__ mtop,
                    float* __restrict__ ctx) {
  int tid = blockIdx.x * 256 + threadIdx.x;
  int s = tid >> 6;
  if (s >= BH * U_) return;
  int d = tid & 63;
  int bh = s / U_;
  int m = mtop[s];
  ctx[(size_t)bh * (L_ * D_) + (size_t)m * D_ + d] = upd[(size_t)s * 64 + d];
}

extern "C" void kernel_launch(void* const* d_in, const int* in_sizes, int n_in,
                              void* d_out, int out_size, void* d_ws, size_t ws_size,
                              hipStream_t stream) {
  const float* q_in = (const float*)d_in[0];
  const float* k_in = (const float*)d_in[1];
  const float* v_in = (const float*)d_in[2];
  const float* Wq   = (const float*)d_in[3];
  const float* Wk   = (const float*)d_in[4];
  const float* Wv   = (const float*)d_in[5];
  const float* Wo   = (const float*)d_in[6];
  const int*   indx = (const int*)d_in[7];
  float* out = (float*)d_out;

  float* ws = (float*)d_ws;
  float* qp   = ws;                         // 16777216 floats (64 MiB) — aliased by ctx later
  float* kp   = ws + 16777216;              // 64 MiB
  float* vp   = ws + 33554432;              // 64 MiB
  float* dotM = ws + 50331648;              // 262144 floats
  float* upd  = ws + 50593792;              // 327680 floats
  int*   mtop = (int*)(ws + 50921472);      // 5120 ints
  float* ctx  = qp;                         // reuse qp region after its last read

  const int M = B_ * L_;                    // 32768

  // projections (f32 — precision needed for exact top-k match)
  gemm_f32<128,128,8,8,8><<<dim3(M/128, HID_/128), 256, 0, stream>>>(q_in, Wq, qp, M, HID_, DIN);
  gemm_f32<128,128,8,8,8><<<dim3(M/128, HID_/128), 256, 0, stream>>>(k_in, Wk, kp, M, HID_, DIN);
  gemm_f32<128,128,8,8,8><<<dim3(M/128, HID_/128), 256, 0, stream>>>(v_in, Wv, vp, M, HID_, DIN);

  // dot + M
  dot_kernel<<<(BH * L_) / 4, 256, 0, stream>>>(qp, kp, indx, dotM);

  // top-40 per (b,h)
  topk_kernel<<<BH, 256, 0, stream>>>(dotM, mtop);

  // masked attention for selected queries
  attn_kernel<<<BH * U_, 256, 0, stream>>>(qp, kp, vp, mtop, upd);

  // cumsum of v -> ctx (overwrites qp region; qp no longer needed)
  cumsum_kernel<<<BH, 256, 0, stream>>>(vp, ctx);

  // scatter attention rows
  scatter_kernel<<<(BH * U_ * 64) / 256, 256, 0, stream>>>(upd, mtop, ctx);

  // out = ctx @ Wo
  gemm_f32<128,64,16,8,4><<<dim3(M/128, 1), 256, 0, stream>>>(ctx, Wo, out, M, 64, HID_);
}

// Round 2
// 1063.932 us; speedup vs baseline: 1.3932x; 1.3932x over previous
//
#include <hip/hip_runtime.h>
#include <hip/hip_bf16.h>
#include <math.h>

#define B_   16
#define L_   2048
#define DIN  512
#define HID_ 512
#define H_   8
#define D_   64
#define U_   40
#define BH   (B_*H_)     // 128

// ---------------- generic f32 tiled GEMM: C(MxN) = A(MxK) @ B(KxN), row-major ----
template<int BM, int BN, int BK, int TM, int TN>
__global__ __launch_bounds__(256)
void gemm_f32(const float* __restrict__ A, const float* __restrict__ Bm,
              float* __restrict__ C, int M, int N, int K) {
  __shared__ float As[BK][BM + 4];
  __shared__ float Bs[BK][BN + 4];
  const int t = threadIdx.x;
  const int row0 = blockIdx.x * BM;
  const int col0 = blockIdx.y * BN;
  const int NTX = BN / TN;
  const int tx = t % NTX, ty = t / NTX;
  float acc[TM][TN];
  #pragma unroll
  for (int i = 0; i < TM; ++i)
    #pragma unroll
    for (int j = 0; j < TN; ++j) acc[i][j] = 0.f;

  for (int k0 = 0; k0 < K; k0 += BK) {
    #pragma unroll
    for (int e = t * 4; e < BM * BK; e += 1024) {
      int r = e / BK, kk = e % BK;   // kk multiple of 4
      float4 v = *reinterpret_cast<const float4*>(&A[(size_t)(row0 + r) * K + k0 + kk]);
      As[kk + 0][r] = v.x; As[kk + 1][r] = v.y; As[kk + 2][r] = v.z; As[kk + 3][r] = v.w;
    }
    #pragma unroll
    for (int e = t * 4; e < BK * BN; e += 1024) {
      int kk = e / BN, c = e % BN;   // c multiple of 4
      *reinterpret_cast<float4*>(&Bs[kk][c]) =
          *reinterpret_cast<const float4*>(&Bm[(size_t)(k0 + kk) * N + col0 + c]);
    }
    __syncthreads();
    #pragma unroll
    for (int k = 0; k < BK; ++k) {
      float a[TM], b[TN];
      #pragma unroll
      for (int i = 0; i < TM; ++i) a[i] = As[k][ty * TM + i];
      #pragma unroll
      for (int j = 0; j < TN; ++j) b[j] = Bs[k][tx * TN + j];
      #pragma unroll
      for (int i = 0; i < TM; ++i)
        #pragma unroll
        for (int j = 0; j < TN; ++j) acc[i][j] += a[i] * b[j];
    }
    __syncthreads();
  }
  #pragma unroll
  for (int i = 0; i < TM; ++i)
    #pragma unroll
    for (int j = 0; j < TN; j += 4) {
      float4 o = make_float4(acc[i][j], acc[i][j+1], acc[i][j+2], acc[i][j+3]);
      *reinterpret_cast<float4*>(&C[(size_t)(row0 + ty * TM + i) * N + col0 + tx * TN + j]) = o;
    }
}

// ---------------- dot[bh,l] = sum_d q[bh,l,d]*k[bh,indx[l],d]; M = dot - dot*(U/L) ----
__global__ __launch_bounds__(256)
void dot_kernel(const float* __restrict__ qp, const float* __restrict__ kp,
                const int* __restrict__ indx, float* __restrict__ dotM) {
  int tid = blockIdx.x * 256 + threadIdx.x;
  int w = tid >> 6;       // dot index in [0, BH*L)
  int lane = tid & 63;
  int bh = w >> 11;       // / 2048
  int l = w & 2047;
  size_t boff = (size_t)bh * (L_ * D_);
  float q = qp[boff + (size_t)l * D_ + lane];
  int ls = indx[l];
  float k = kp[boff + (size_t)ls * D_ + lane];
  float p = q * k;
  #pragma unroll
  for (int off = 32; off >= 1; off >>= 1) p += __shfl_xor(p, off, 64);
  if (lane == 0) {
    const float cUL = 40.0f / 2048.0f;
    dotM[(size_t)bh * L_ + l] = p - p * cUL;
  }
}

// ---------------- per-(b,h) top-40 by value, ties -> lower index --------------------
__global__ __launch_bounds__(256)
void topk_kernel(const float* __restrict__ dotM, int* __restrict__ mtop) {
  __shared__ float vals[L_];
  __shared__ float rv[256];
  __shared__ int   ri[256];
  int bh = blockIdx.x, t = threadIdx.x;
  const float* row = dotM + (size_t)bh * L_;
  for (int i = t; i < L_; i += 256) vals[i] = row[i];
  __syncthreads();
  for (int u = 0; u < U_; ++u) {
    float bv = -INFINITY; int bi = 0x7fffffff;
    for (int i = t; i < L_; i += 256) {
      float v = vals[i];
      if (v > bv || (v == bv && i < bi)) { bv = v; bi = i; }
    }
    rv[t] = bv; ri[t] = bi;
    __syncthreads();
    for (int s = 128; s > 0; s >>= 1) {
      if (t < s) {
        float v2 = rv[t + s]; int i2 = ri[t + s];
        if (v2 > rv[t] || (v2 == rv[t] && i2 < ri[t])) { rv[t] = v2; ri[t] = i2; }
      }
      __syncthreads();
    }
    if (t == 0) { mtop[bh * U_ + u] = ri[0]; vals[ri[0]] = -INFINITY; }
    __syncthreads();
  }
}

// ---------------- gather selected q rows into compact buffer ------------------------
__global__ __launch_bounds__(256)
void gather_q_kernel(const float* __restrict__ qp, const int* __restrict__ mtop,
                     float* __restrict__ qred) {
  int tid = blockIdx.x * 256 + threadIdx.x;   // 5120*64 total
  int s = tid >> 6;        // bh*U + u
  int d = tid & 63;
  int bh = s / U_;
  int m = mtop[s];
  qred[(size_t)s * 64 + d] = qp[(size_t)bh * (L_ * D_) + (size_t)m * D_ + d];
}

// ---------------- scores: S[bh][u][l] = mask( (q_red[u] . k[l]) / 8 ) ---------------
// grid (BH, L/64), block 256 (4 waves x 10 u's each), lane = l within tile
__global__ __launch_bounds__(256)
void scores_kernel(const float* __restrict__ qred, const float* __restrict__ kp,
                   const int* __restrict__ mtop, float* __restrict__ S) {
  __shared__ float kt[64][65];     // +1 pad: 2-way conflicts only (free)
  __shared__ float qs[U_][64];
  __shared__ int   ms[U_];
  const int bh = blockIdx.x;
  const int l0 = blockIdx.y * 64;
  const int t = threadIdx.x;
  const size_t boff = (size_t)bh * (L_ * D_);

  #pragma unroll
  for (int e = t * 4; e < 64 * 64; e += 1024) {
    int r = e >> 6, c = e & 63;
    float4 v = *reinterpret_cast<const float4*>(&kp[boff + (size_t)(l0 + r) * 64 + c]);
    kt[r][c] = v.x; kt[r][c+1] = v.y; kt[r][c+2] = v.z; kt[r][c+3] = v.w;
  }
  #pragma unroll
  for (int e = t; e < U_ * 64; e += 256) {
    qs[e >> 6][e & 63] = qred[(size_t)(bh * U_) * 64 + e];
  }
  if (t < U_) ms[t] = mtop[bh * U_ + t];
  __syncthreads();

  const int lane = t & 63;         // l - l0
  const int u0 = (t >> 6) * 10;    // wave's 10 u's
  float s[10];
  #pragma unroll
  for (int i = 0; i < 10; ++i) s[i] = 0.f;
  #pragma unroll
  for (int d = 0; d < 64; ++d) {
    float kd = kt[lane][d];
    #pragma unroll
    for (int i = 0; i < 10; ++i) s[i] += qs[u0 + i][d] * kd;   // qs read = broadcast
  }
  const int l = l0 + lane;
  #pragma unroll
  for (int i = 0; i < 10; ++i) {
    float val = s[i] * 0.125f;
    if (l > ms[u0 + i]) val = -INFINITY;
    S[((size_t)(bh * U_) + u0 + i) * L_ + l] = val;
  }
}

// ---------------- row softmax over l (in place), rows = BH*U --------------------------
__global__ __launch_bounds__(256)
void softmax_kernel(float* __restrict__ S) {
  __shared__ float red[4];
  const int row = blockIdx.x;
  const int t = threadIdx.x;
  float4* rp = reinterpret_cast<float4*>(S + (size_t)row * L_);
  float4 a = rp[t], b = rp[t + 256];
  float m = fmaxf(fmaxf(fmaxf(a.x, a.y), fmaxf(a.z, a.w)),
                  fmaxf(fmaxf(b.x, b.y), fmaxf(b.z, b.w)));
  #pragma unroll
  for (int off = 32; off >= 1; off >>= 1) m = fmaxf(m, __shfl_xor(m, off, 64));
  if ((t & 63) == 0) red[t >> 6] = m;
  __syncthreads();
  m = fmaxf(fmaxf(red[0], red[1]), fmaxf(red[2], red[3]));
  __syncthreads();
  a.x = expf(a.x - m); a.y = expf(a.y - m); a.z = expf(a.z - m); a.w = expf(a.w - m);
  b.x = expf(b.x - m); b.y = expf(b.y - m); b.z = expf(b.z - m); b.w = expf(b.w - m);
  float s = a.x + a.y + a.z + a.w + b.x + b.y + b.z + b.w;
  #pragma unroll
  for (int off = 32; off >= 1; off >>= 1) s += __shfl_xor(s, off, 64);
  if ((t & 63) == 0) red[t >> 6] = s;
  __syncthreads();
  s = red[0] + red[1] + red[2] + red[3];
  float inv = 1.0f / s;
  a.x *= inv; a.y *= inv; a.z *= inv; a.w *= inv;
  b.x *= inv; b.y *= inv; b.z *= inv; b.w *= inv;
  rp[t] = a; rp[t + 256] = b;
}

// ---------------- PV partial: per (bh, l-range of 256) compute partial upd[40][64] ---
// grid (BH, 8), block 256, lane = d, wave's 10 u's
__global__ __launch_bounds__(256)
void pv_kernel(const float* __restrict__ S, const float* __restrict__ vp,
               float* __restrict__ partial) {
  __shared__ float vt[64][65];
  __shared__ float pt[U_][64];
  const int bh = blockIdx.x;
  const int c8 = blockIdx.y;       // which 256-wide l range
  const int t = threadIdx.x;
  const int lane = t & 63;         // d
  const int u0 = (t >> 6) * 10;
  const size_t boff = (size_t)bh * (L_ * D_);
  float acc[10];
  #pragma unroll
  for (int i = 0; i < 10; ++i) acc[i] = 0.f;

  for (int cc = 0; cc < 4; ++cc) {
    const int l0 = c8 * 256 + cc * 64;
    #pragma unroll
    for (int e = t * 4; e < 64 * 64; e += 1024) {
      int r = e >> 6, c = e & 63;
      float4 v = *reinterpret_cast<const float4*>(&vp[boff + (size_t)(l0 + r) * 64 + c]);
      vt[r][c] = v.x; vt[r][c+1] = v.y; vt[r][c+2] = v.z; vt[r][c+3] = v.w;
    }
    #pragma unroll
    for (int e = t; e < U_ * 64; e += 256) {
      int u = e >> 6, lc = e & 63;
      pt[u][lc] = S[((size_t)(bh * U_) + u) * L_ + l0 + lc];
    }
    __syncthreads();
    #pragma unroll
    for (int lc = 0; lc < 64; ++lc) {
      float vd = vt[lc][lane];
      #pragma unroll
      for (int i = 0; i < 10; ++i) acc[i] += pt[u0 + i][lc] * vd;  // pt read = broadcast
    }
    __syncthreads();
  }
  #pragma unroll
  for (int i = 0; i < 10; ++i) {
    partial[(((size_t)bh * 8 + c8) * U_ + u0 + i) * 64 + lane] = acc[i];
  }
}

// ---------------- reduce 8 partials -> upd ------------------------------------------
__global__ __launch_bounds__(256)
void pv_reduce_kernel(const float* __restrict__ partial, float* __restrict__ upd) {
  int tid = blockIdx.x * 256 + threadIdx.x;   // 5120*64
  int s = tid >> 6;        // bh*U + u
  int d = tid & 63;
  int bh = s / U_;
  int u = s - bh * U_;
  float acc = 0.f;
  #pragma unroll
  for (int c = 0; c < 8; ++c)
    acc += partial[(((size_t)bh * 8 + c) * U_ + u) * 64 + d];
  upd[(size_t)s * 64 + d] = acc;
}

// ---------------- inclusive cumsum of v along l (per bh, per d) ---------------------
__global__ __launch_bounds__(256)
void cumsum_kernel(const float* __restrict__ vp, float* __restrict__ ctx) {
  __shared__ float segsum[4][64];
  int bh = blockIdx.x, t = threadIdx.x;
  int lane = t & 63, seg = t >> 6;
  size_t boff = (size_t)bh * (L_ * D_);
  const int SEG = L_ / 4;   // 512
  int l0 = seg * SEG;
  float s = 0.f;
  for (int l = l0; l < l0 + SEG; ++l) s += vp[boff + (size_t)l * D_ + lane];
  segsum[seg][lane] = s;
  __syncthreads();
  float run = 0.f;
  for (int ss = 0; ss < seg; ++ss) run += segsum[ss][lane];
  for (int l = l0; l < l0 + SEG; ++l) {
    run += vp[boff + (size_t)l * D_ + lane];
    ctx[boff + (size_t)l * D_ + lane] = run;
  }
}

// ---------------- scatter upd rows into ctx at m_top --------------------------------
__global__ __launch_bounds__(256)
void scatter_kernel(const float* __restrict__ upd, const int* __restrict__ mtop,
                    float* __restrict__ ctx) {
  int tid = blockIdx.x * 256 + threadIdx.x;
  int s = tid >> 6;
  if (s >= BH * U_) return;
  int d = tid & 63;
  int bh = s / U_;
  int m = mtop[s];
  ctx[(size_t)bh * (L_ * D_) + (size_t)m * D_ + d] = upd[(size_t)s * 64 + d];
}

extern "C" void kernel_launch(void* const* d_in, const int* in_sizes, int n_in,
                              void* d_out, int out_size, void* d_ws, size_t ws_size,
                              hipStream_t stream) {
  const float* q_in = (const float*)d_in[0];
  const float* k_in = (const float*)d_in[1];
  const float* v_in = (const float*)d_in[2];
  const float* Wq   = (const float*)d_in[3];
  const float* Wk   = (const float*)d_in[4];
  const float* Wv   = (const float*)d_in[5];
  const float* Wo   = (const float*)d_in[6];
  const int*   indx = (const int*)d_in[7];
  float* out = (float*)d_out;

  float* ws = (float*)d_ws;
  float* qp   = ws;                         // 16,777,216 floats (64 MiB)
  float* kp   = ws + 16777216;              // 64 MiB
  float* vp   = ws + 33554432;              // 64 MiB
  float* dotM = ws + 50331648;              // 262,144 floats
  float* upd  = ws + 50593792;              // 327,680 floats
  int*   mtop = (int*)(ws + 50921472);      // 5,120 ints
  // Sub-allocations INSIDE the qp region (qp is dead after gather_q; the whole
  // region is later overwritten by cumsum as ctx):
  float* qred    = qp;                      // 327,680 floats
  float* S       = qp + 327680;             // 10,485,760 floats (BH*U_*L_)
  float* partial = qp + 10813440;           // 2,621,440 floats (BH*8*U_*64)
  float* ctx  = qp;                         // cumsum output overwrites qp region

  const int M = B_ * L_;                    // 32768

  // projections (f32 — precision needed for exact top-k match)
  gemm_f32<128,128,8,8,8><<<dim3(M/128, HID_/128), 256, 0, stream>>>(q_in, Wq, qp, M, HID_, DIN);
  gemm_f32<128,128,8,8,8><<<dim3(M/128, HID_/128), 256, 0, stream>>>(k_in, Wk, kp, M, HID_, DIN);
  gemm_f32<128,128,8,8,8><<<dim3(M/128, HID_/128), 256, 0, stream>>>(v_in, Wv, vp, M, HID_, DIN);

  // dot + M
  dot_kernel<<<(BH * L_) / 4, 256, 0, stream>>>(qp, kp, indx, dotM);

  // top-40 per (b,h)
  topk_kernel<<<BH, 256, 0, stream>>>(dotM, mtop);

  // gather q_red (qp region free for reuse after this)
  gather_q_kernel<<<(BH * U_ * 64) / 256, 256, 0, stream>>>(qp, mtop, qred);

  // scores + mask
  scores_kernel<<<dim3(BH, L_ / 64), 256, 0, stream>>>(qred, kp, mtop, S);

  // row softmax (in place)
  softmax_kernel<<<BH * U_, 256, 0, stream>>>(S);

  // PV partials + reduce
  pv_kernel<<<dim3(BH, 8), 256, 0, stream>>>(S, vp, partial);
  pv_reduce_kernel<<<(BH * U_ * 64) / 256, 256, 0, stream>>>(partial, upd);

  // cumsum of v -> ctx (overwrites qp region)
  cumsum_kernel<<<BH, 256, 0, stream>>>(vp, ctx);

  // scatter attention rows
  scatter_kernel<<<(BH * U_ * 64) / 256, 256, 0, stream>>>(upd, mtop, ctx);

  // out = ctx @ Wo
  gemm_f32<128,64,16,8,4><<<dim3(M/128, 1), 256, 0, stream>>>(ctx, Wo, out, M, 64, HID_);
}

// Round 3
// 632.733 us; speedup vs baseline: 2.3426x; 1.6815x over previous
//
#include <hip/hip_runtime.h>
#include <hip/hip_bf16.h>
#include <math.h>

#define B_   16
#define L_   2048
#define DIN  512
#define HID_ 512
#define H_   8
#define D_   64
#define U_   40
#define BH   (B_*H_)     // 128

typedef unsigned short u16;
typedef __bf16 bf16x8 __attribute__((ext_vector_type(8)));
typedef float f32x4 __attribute__((ext_vector_type(4)));

__device__ __forceinline__ u16 f2bf_rne(float x) {
  unsigned u = __float_as_uint(x);
  unsigned r = (u + 0x7FFFu + ((u >> 16) & 1u)) >> 16;
  return (u16)r;
}
__device__ __forceinline__ float bf2f(u16 h) {
  return __uint_as_float(((unsigned)h) << 16);
}
__device__ __forceinline__ void gload16(const u16* g, u16* l) {
  __builtin_amdgcn_global_load_lds(
      (__attribute__((address_space(1))) void*)(g),
      (__attribute__((address_space(3))) void*)(l), 16, 0, 0);
}

// ---------------- weight split+transpose: W f32 [512][512] -> Bt bf16 [512][1024] ----
// Bt[n][kb*64 + swz] : per 32-row chunk kb, cols 0..31 = hi, 32..63 = lo,
// with 16B-slot XOR swizzle  slot ^= (n&7)  baked into the global layout.
__global__ __launch_bounds__(256)
void wsplit_kernel(const float* __restrict__ W, u16* __restrict__ Bt) {
  int tid = blockIdx.x * 256 + threadIdx.x;      // 262144 threads
  int n = tid & 511, k = tid >> 9;
  float a = W[(size_t)k * 512 + n];
  u16 hi = f2bf_rne(a);
  u16 lo = f2bf_rne(a - bf2f(hi));
  int kb = k >> 5, kc = k & 31;
  int slotH = kc >> 3, wi = kc & 7;
  int swzH = (slotH     ^ (n & 7)) << 3;
  int swzL = ((4+slotH) ^ (n & 7)) << 3;
  Bt[(size_t)n * 1024 + kb * 64 + swzH + wi] = hi;
  Bt[(size_t)n * 1024 + kb * 64 + swzL + wi] = lo;
}

// ---------------- projection GEMM: C[M][512] = A_f32[M][512] @ W  (3-term bf16 split)
// BM=BN=128, 16 supersteps of 32 source-cols; A split in-kernel, B via global_load_lds.
__global__ __launch_bounds__(256, 2)
void gemm_proj(const float* __restrict__ A, const u16* __restrict__ Bt,
               float* __restrict__ C) {
  __shared__ u16 As[128 * 64];   // [row][64]: hi(32)+lo(32), slot-swizzled
  __shared__ u16 Bs[128 * 64];   // [col][64]: hi+lo, swizzle pre-baked in Bt
  const int t = threadIdx.x;
  const int w = t >> 6, lane = t & 63;
  const int lhi = lane >> 4, l16 = lane & 15;
  const int row0 = blockIdx.x * 128, col0 = blockIdx.y * 128;
  const int wrow = (w >> 1) * 64, wcol = (w & 1) * 64;

  // B staging addresses: instr covers 8 n-rows x 128B (lane>>3 = row, lane&7 = 16B slot)
  const u16* gB = Bt + (size_t)(col0 + w * 32 + (lane >> 3)) * 1024 + (lane & 7) * 8;
  u16* lB = &Bs[(w * 32) * 64];

  f32x4 acc[4][4];
  #pragma unroll
  for (int i = 0; i < 4; ++i)
    #pragma unroll
    for (int j = 0; j < 4; ++j) acc[i][j] = (f32x4){0.f, 0.f, 0.f, 0.f};

  for (int kb = 0; kb < 16; ++kb) {
    // stage B tile (linear copy of pre-swizzled rows)
    #pragma unroll
    for (int i = 0; i < 4; ++i)
      gload16(gB + kb * 64 + (size_t)i * 8 * 1024, lB + i * 8 * 64);
    // stage A tile: load f32, split hi/lo, swizzled ds_write
    #pragma unroll
    for (int i = 0; i < 4; ++i) {
      int r  = (t >> 3) + 32 * i;
      int c4 = (t & 7) * 4;                      // 0,4,...,28
      float4 v = *reinterpret_cast<const float4*>(
          &A[(size_t)(row0 + r) * 512 + kb * 32 + c4]);
      ushort4 h4, lo4;
      { u16 h = f2bf_rne(v.x); h4.x = h; lo4.x = f2bf_rne(v.x - bf2f(h)); }
      { u16 h = f2bf_rne(v.y); h4.y = h; lo4.y = f2bf_rne(v.y - bf2f(h)); }
      { u16 h = f2bf_rne(v.z); h4.z = h; lo4.z = f2bf_rne(v.z - bf2f(h)); }
      { u16 h = f2bf_rne(v.w); h4.w = h; lo4.w = f2bf_rne(v.w - bf2f(h)); }
      int slotH = c4 >> 3, wi = c4 & 7;          // wi in {0,4}
      int baseH = r * 64 + (((slotH)     ^ (r & 7)) << 3) + wi;
      int baseL = r * 64 + (((4 + slotH) ^ (r & 7)) << 3) + wi;
      *reinterpret_cast<ushort4*>(&As[baseH]) = h4;
      *reinterpret_cast<ushort4*>(&As[baseL]) = lo4;
    }
    __syncthreads();

#define PASS(APART, BPART)                                                      \
    { bf16x8 af[4], bfr[4];                                                     \
      _Pragma("unroll") for (int i = 0; i < 4; ++i) {                           \
        int ra = wrow + i * 16 + l16;                                           \
        af[i] = *reinterpret_cast<const bf16x8*>(                               \
            &As[ra * 64 + ((((APART) + lhi) ^ (ra & 7)) << 3)]); }              \
      _Pragma("unroll") for (int j = 0; j < 4; ++j) {                           \
        int cb = wcol + j * 16 + l16;                                           \
        bfr[j] = *reinterpret_cast<const bf16x8*>(                              \
            &Bs[cb * 64 + ((((BPART) + lhi) ^ (cb & 7)) << 3)]); }              \
      _Pragma("unroll") for (int i = 0; i < 4; ++i)                             \
        _Pragma("unroll") for (int j = 0; j < 4; ++j)                           \
          acc[i][j] = __builtin_amdgcn_mfma_f32_16x16x32_bf16(                  \
              af[i], bfr[j], acc[i][j], 0, 0, 0); }

    PASS(0, 0)   // Ah * Bh
    PASS(0, 4)   // Ah * Bl
    PASS(4, 0)   // Al * Bh
#undef PASS
    __syncthreads();
  }
  // epilogue: D[row]=lhi*4+r, col=l16 per 16x16 frag
  #pragma unroll
  for (int i = 0; i < 4; ++i)
    #pragma unroll
    for (int j = 0; j < 4; ++j)
      #pragma unroll
      for (int r = 0; r < 4; ++r)
        C[(size_t)(row0 + wrow + i * 16 + lhi * 4 + r) * 512
          + col0 + wcol + j * 16 + l16] = acc[i][j][r];
}

// ---------------- generic f32 tiled GEMM (kept for the small final GEMM) ------------
template<int BM, int BN, int BK, int TM, int TN>
__global__ __launch_bounds__(256)
void gemm_f32(const float* __restrict__ A, const float* __restrict__ Bm,
              float* __restrict__ C, int M, int N, int K) {
  __shared__ float As[BK][BM + 4];
  __shared__ float Bs[BK][BN + 4];
  const int t = threadIdx.x;
  const int row0 = blockIdx.x * BM;
  const int col0 = blockIdx.y * BN;
  const int NTX = BN / TN;
  const int tx = t % NTX, ty = t / NTX;
  float acc[TM][TN];
  #pragma unroll
  for (int i = 0; i < TM; ++i)
    #pragma unroll
    for (int j = 0; j < TN; ++j) acc[i][j] = 0.f;

  for (int k0 = 0; k0 < K; k0 += BK) {
    #pragma unroll
    for (int e = t * 4; e < BM * BK; e += 1024) {
      int r = e / BK, kk = e % BK;
      float4 v = *reinterpret_cast<const float4*>(&A[(size_t)(row0 + r) * K + k0 + kk]);
      As[kk + 0][r] = v.x; As[kk + 1][r] = v.y; As[kk + 2][r] = v.z; As[kk + 3][r] = v.w;
    }
    #pragma unroll
    for (int e = t * 4; e < BK * BN; e += 1024) {
      int kk = e / BN, c = e % BN;
      *reinterpret_cast<float4*>(&Bs[kk][c]) =
          *reinterpret_cast<const float4*>(&Bm[(size_t)(k0 + kk) * N + col0 + c]);
    }
    __syncthreads();
    #pragma unroll
    for (int k = 0; k < BK; ++k) {
      float a[TM], b[TN];
      #pragma unroll
      for (int i = 0; i < TM; ++i) a[i] = As[k][ty * TM + i];
      #pragma unroll
      for (int j = 0; j < TN; ++j) b[j] = Bs[k][tx * TN + j];
      #pragma unroll
      for (int i = 0; i < TM; ++i)
        #pragma unroll
        for (int j = 0; j < TN; ++j) acc[i][j] += a[i] * b[j];
    }
    __syncthreads();
  }
  #pragma unroll
  for (int i = 0; i < TM; ++i)
    #pragma unroll
    for (int j = 0; j < TN; j += 4) {
      float4 o = make_float4(acc[i][j], acc[i][j+1], acc[i][j+2], acc[i][j+3]);
      *reinterpret_cast<float4*>(&C[(size_t)(row0 + ty * TM + i) * N + col0 + tx * TN + j]) = o;
    }
}

// ---------------- dot[bh,l] = sum_d q[bh,l,d]*k[bh,indx[l],d]; M = dot - dot*(U/L) ----
__global__ __launch_bounds__(256)
void dot_kernel(const float* __restrict__ qp, const float* __restrict__ kp,
                const int* __restrict__ indx, float* __restrict__ dotM) {
  int tid = blockIdx.x * 256 + threadIdx.x;
  int w = tid >> 6;
  int lane = tid & 63;
  int bh = w >> 11;
  int l = w & 2047;
  size_t boff = (size_t)bh * (L_ * D_);
  float q = qp[boff + (size_t)l * D_ + lane];
  int ls = indx[l];
  float k = kp[boff + (size_t)ls * D_ + lane];
  float p = q * k;
  #pragma unroll
  for (int off = 32; off >= 1; off >>= 1) p += __shfl_xor(p, off, 64);
  if (lane == 0) {
    const float cUL = 40.0f / 2048.0f;
    dotM[(size_t)bh * L_ + l] = p - p * cUL;
  }
}

// ---------------- per-(b,h) top-40 by value, ties -> lower index --------------------
__global__ __launch_bounds__(256)
void topk_kernel(const float* __restrict__ dotM, int* __restrict__ mtop) {
  __shared__ float vals[L_];
  __shared__ float rv[256];
  __shared__ int   ri[256];
  int bh = blockIdx.x, t = threadIdx.x;
  const float* row = dotM + (size_t)bh * L_;
  for (int i = t; i < L_; i += 256) vals[i] = row[i];
  __syncthreads();
  for (int u = 0; u < U_; ++u) {
    float bv = -INFINITY; int bi = 0x7fffffff;
    for (int i = t; i < L_; i += 256) {
      float v = vals[i];
      if (v > bv || (v == bv && i < bi)) { bv = v; bi = i; }
    }
    rv[t] = bv; ri[t] = bi;
    __syncthreads();
    for (int s = 128; s > 0; s >>= 1) {
      if (t < s) {
        float v2 = rv[t + s]; int i2 = ri[t + s];
        if (v2 > rv[t] || (v2 == rv[t] && i2 < ri[t])) { rv[t] = v2; ri[t] = i2; }
      }
      __syncthreads();
    }
    if (t == 0) { mtop[bh * U_ + u] = ri[0]; vals[ri[0]] = -INFINITY; }
    __syncthreads();
  }
}

// ---------------- gather selected q rows into compact buffer ------------------------
__global__ __launch_bounds__(256)
void gather_q_kernel(const float* __restrict__ qp, const int* __restrict__ mtop,
                     float* __restrict__ qred) {
  int tid = blockIdx.x * 256 + threadIdx.x;
  int s = tid >> 6;
  int d = tid & 63;
  int bh = s / U_;
  int m = mtop[s];
  qred[(size_t)s * 64 + d] = qp[(size_t)bh * (L_ * D_) + (size_t)m * D_ + d];
}

// ---------------- scores: S[bh][u][l] = mask( (q_red[u] . k[l]) / 8 ) ---------------
__global__ __launch_bounds__(256)
void scores_kernel(const float* __restrict__ qred, const float* __restrict__ kp,
                   const int* __restrict__ mtop, float* __restrict__ S) {
  __shared__ float kt[64][65];
  __shared__ float qs[U_][64];
  __shared__ int   ms[U_];
  const int bh = blockIdx.x;
  const int l0 = blockIdx.y * 64;
  const int t = threadIdx.x;
  const size_t boff = (size_t)bh * (L_ * D_);

  #pragma unroll
  for (int e = t * 4; e < 64 * 64; e += 1024) {
    int r = e >> 6, c = e & 63;
    float4 v = *reinterpret_cast<const float4*>(&kp[boff + (size_t)(l0 + r) * 64 + c]);
    kt[r][c] = v.x; kt[r][c+1] = v.y; kt[r][c+2] = v.z; kt[r][c+3] = v.w;
  }
  #pragma unroll
  for (int e = t; e < U_ * 64; e += 256) {
    qs[e >> 6][e & 63] = qred[(size_t)(bh * U_) * 64 + e];
  }
  if (t < U_) ms[t] = mtop[bh * U_ + t];
  __syncthreads();

  const int lane = t & 63;
  const int u0 = (t >> 6) * 10;
  float s[10];
  #pragma unroll
  for (int i = 0; i < 10; ++i) s[i] = 0.f;
  #pragma unroll
  for (int d = 0; d < 64; ++d) {
    float kd = kt[lane][d];
    #pragma unroll
    for (int i = 0; i < 10; ++i) s[i] += qs[u0 + i][d] * kd;
  }
  const int l = l0 + lane;
  #pragma unroll
  for (int i = 0; i < 10; ++i) {
    float val = s[i] * 0.125f;
    if (l > ms[u0 + i]) val = -INFINITY;
    S[((size_t)(bh * U_) + u0 + i) * L_ + l] = val;
  }
}

// ---------------- row softmax over l (in place), rows = BH*U ------------------------
__global__ __launch_bounds__(256)
void softmax_kernel(float* __restrict__ S) {
  __shared__ float red[4];
  const int row = blockIdx.x;
  const int t = threadIdx.x;
  float4* rp = reinterpret_cast<float4*>(S + (size_t)row * L_);
  float4 a = rp[t], b = rp[t + 256];
  float m = fmaxf(fmaxf(fmaxf(a.x, a.y), fmaxf(a.z, a.w)),
                  fmaxf(fmaxf(b.x, b.y), fmaxf(b.z, b.w)));
  #pragma unroll
  for (int off = 32; off >= 1; off >>= 1) m = fmaxf(m, __shfl_xor(m, off, 64));
  if ((t & 63) == 0) red[t >> 6] = m;
  __syncthreads();
  m = fmaxf(fmaxf(red[0], red[1]), fmaxf(red[2], red[3]));
  __syncthreads();
  a.x = expf(a.x - m); a.y = expf(a.y - m); a.z = expf(a.z - m); a.w = expf(a.w - m);
  b.x = expf(b.x - m); b.y = expf(b.y - m); b.z = expf(b.z - m); b.w = expf(b.w - m);
  float s = a.x + a.y + a.z + a.w + b.x + b.y + b.z + b.w;
  #pragma unroll
  for (int off = 32; off >= 1; off >>= 1) s += __shfl_xor(s, off, 64);
  if ((t & 63) == 0) red[t >> 6] = s;
  __syncthreads();
  s = red[0] + red[1] + red[2] + red[3];
  float inv = 1.0f / s;
  a.x *= inv; a.y *= inv; a.z *= inv; a.w *= inv;
  b.x *= inv; b.y *= inv; b.z *= inv; b.w *= inv;
  rp[t] = a; rp[t + 256] = b;
}

// ---------------- PV partial: per (bh, l-range of 256) partial upd[40][64] ----------
__global__ __launch_bounds__(256)
void pv_kernel(const float* __restrict__ S, const float* __restrict__ vp,
               float* __restrict__ partial) {
  __shared__ float vt[64][65];
  __shared__ float pt[U_][64];
  const int bh = blockIdx.x;
  const int c8 = blockIdx.y;
  const int t = threadIdx.x;
  const int lane = t & 63;
  const int u0 = (t >> 6) * 10;
  const size_t boff = (size_t)bh * (L_ * D_);
  float acc[10];
  #pragma unroll
  for (int i = 0; i < 10; ++i) acc[i] = 0.f;

  for (int cc = 0; cc < 4; ++cc) {
    const int l0 = c8 * 256 + cc * 64;
    #pragma unroll
    for (int e = t * 4; e < 64 * 64; e += 1024) {
      int r = e >> 6, c = e & 63;
      float4 v = *reinterpret_cast<const float4*>(&vp[boff + (size_t)(l0 + r) * 64 + c]);
      vt[r][c] = v.x; vt[r][c+1] = v.y; vt[r][c+2] = v.z; vt[r][c+3] = v.w;
    }
    #pragma unroll
    for (int e = t; e < U_ * 64; e += 256) {
      int u = e >> 6, lc = e & 63;
      pt[u][lc] = S[((size_t)(bh * U_) + u) * L_ + l0 + lc];
    }
    __syncthreads();
    #pragma unroll
    for (int lc = 0; lc < 64; ++lc) {
      float vd = vt[lc][lane];
      #pragma unroll
      for (int i = 0; i < 10; ++i) acc[i] += pt[u0 + i][lc] * vd;
    }
    __syncthreads();
  }
  #pragma unroll
  for (int i = 0; i < 10; ++i) {
    partial[(((size_t)bh * 8 + c8) * U_ + u0 + i) * 64 + lane] = acc[i];
  }
}

// ---------------- reduce 8 partials -> upd ------------------------------------------
__global__ __launch_bounds__(256)
void pv_reduce_kernel(const float* __restrict__ partial, float* __restrict__ upd) {
  int tid = blockIdx.x * 256 + threadIdx.x;
  int s = tid >> 6;
  int d = tid & 63;
  int bh = s / U_;
  int u = s - bh * U_;
  float acc = 0.f;
  #pragma unroll
  for (int c = 0; c < 8; ++c)
    acc += partial[(((size_t)bh * 8 + c) * U_ + u) * 64 + d];
  upd[(size_t)s * 64 + d] = acc;
}

// ---------------- inclusive cumsum of v along l (per bh, per d) ---------------------
__global__ __launch_bounds__(256)
void cumsum_kernel(const float* __restrict__ vp, float* __restrict__ ctx) {
  __shared__ float segsum[4][64];
  int bh = blockIdx.x, t = threadIdx.x;
  int lane = t & 63, seg = t >> 6;
  size_t boff = (size_t)bh * (L_ * D_);
  const int SEG = L_ / 4;
  int l0 = seg * SEG;
  float s = 0.f;
  for (int l = l0; l < l0 + SEG; ++l) s += vp[boff + (size_t)l * D_ + lane];
  segsum[seg][lane] = s;
  __syncthreads();
  float run = 0.f;
  for (int ss = 0; ss < seg; ++ss) run += segsum[ss][lane];
  for (int l = l0; l < l0 + SEG; ++l) {
    run += vp[boff + (size_t)l * D_ + lane];
    ctx[boff + (size_t)l * D_ + lane] = run;
  }
}

// ---------------- scatter upd rows into ctx at m_top --------------------------------
__global__ __launch_bounds__(256)
void scatter_kernel(const float* __restrict__ upd, const int* __restrict__ mtop,
                    float* __restrict__ ctx) {
  int tid = blockIdx.x * 256 + threadIdx.x;
  int s = tid >> 6;
  if (s >= BH * U_) return;
  int d = tid & 63;
  int bh = s / U_;
  int m = mtop[s];
  ctx[(size_t)bh * (L_ * D_) + (size_t)m * D_ + d] = upd[(size_t)s * 64 + d];
}

extern "C" void kernel_launch(void* const* d_in, const int* in_sizes, int n_in,
                              void* d_out, int out_size, void* d_ws, size_t ws_size,
                              hipStream_t stream) {
  const float* q_in = (const float*)d_in[0];
  const float* k_in = (const float*)d_in[1];
  const float* v_in = (const float*)d_in[2];
  const float* Wq   = (const float*)d_in[3];
  const float* Wk   = (const float*)d_in[4];
  const float* Wv   = (const float*)d_in[5];
  const float* Wo   = (const float*)d_in[6];
  const int*   indx = (const int*)d_in[7];
  float* out = (float*)d_out;

  float* ws = (float*)d_ws;
  float* qp   = ws;                         // 16,777,216 floats
  float* kp   = ws + 16777216;
  float* vp   = ws + 33554432;
  float* dotM = ws + 50331648;              // 262,144 floats (1 MB)
  float* upd  = ws + 50593792;              // 327,680 floats
  int*   mtop = (int*)(ws + 50921472);      // 5,120 ints
  // Bt (split weights, 1 MB) aliases dotM: dotM is only written AFTER projections.
  u16*   Bt   = (u16*)dotM;
  // attention scratch inside qp region (dead between gather_q and cumsum):
  float* qred    = qp;
  float* S       = qp + 327680;
  float* partial = qp + 10813440;
  float* ctx  = qp;

  const int M = B_ * L_;                    // 32768

  // projections via 3-term bf16-split MFMA (Bt buffer reused serially)
  wsplit_kernel<<<1024, 256, 0, stream>>>(Wq, Bt);
  gemm_proj<<<dim3(M / 128, 4), 256, 0, stream>>>(q_in, Bt, qp);
  wsplit_kernel<<<1024, 256, 0, stream>>>(Wk, Bt);
  gemm_proj<<<dim3(M / 128, 4), 256, 0, stream>>>(k_in, Bt, kp);
  wsplit_kernel<<<1024, 256, 0, stream>>>(Wv, Bt);
  gemm_proj<<<dim3(M / 128, 4), 256, 0, stream>>>(v_in, Bt, vp);

  // dot + M  (overwrites the Bt alias — Bt is dead now)
  dot_kernel<<<(BH * L_) / 4, 256, 0, stream>>>(qp, kp, indx, dotM);

  // top-40 per (b,h)
  topk_kernel<<<BH, 256, 0, stream>>>(dotM, mtop);

  // gather q_red
  gather_q_kernel<<<(BH * U_ * 64) / 256, 256, 0, stream>>>(qp, mtop, qred);

  // scores + mask
  scores_kernel<<<dim3(BH, L_ / 64), 256, 0, stream>>>(qred, kp, mtop, S);

  // row softmax (in place)
  softmax_kernel<<<BH * U_, 256, 0, stream>>>(S);

  // PV partials + reduce
  pv_kernel<<<dim3(BH, 8), 256, 0, stream>>>(S, vp, partial);
  pv_reduce_kernel<<<(BH * U_ * 64) / 256, 256, 0, stream>>>(partial, upd);

  // cumsum of v -> ctx (overwrites qp region)
  cumsum_kernel<<<BH, 256, 0, stream>>>(vp, ctx);

  // scatter attention rows
  scatter_kernel<<<(BH * U_ * 64) / 256, 256, 0, stream>>>(upd, mtop, ctx);

  // out = ctx @ Wo
  gemm_f32<128,64,16,8,4><<<dim3(M / 128, 1), 256, 0, stream>>>(ctx, Wo, out, M, 64, HID_);
}

// Round 4
// 576.484 us; speedup vs baseline: 2.5712x; 1.0976x over previous
//
#include <hip/hip_runtime.h>
#include <hip/hip_bf16.h>
#include <math.h>

#define B_   16
#define L_   2048
#define DIN  512
#define HID_ 512
#define H_   8
#define D_   64
#define U_   40
#define BH   (B_*H_)     // 128

typedef unsigned short u16;
typedef unsigned int u32;
typedef __bf16 bf16x8 __attribute__((ext_vector_type(8)));
typedef float f32x4 __attribute__((ext_vector_type(4)));

__device__ __forceinline__ u16 f2bf_rne(float x) {
  unsigned u = __float_as_uint(x);
  unsigned r = (u + 0x7FFFu + ((u >> 16) & 1u)) >> 16;
  return (u16)r;
}
__device__ __forceinline__ float bf2f(u16 h) {
  return __uint_as_float(((unsigned)h) << 16);
}
__device__ __forceinline__ float bflo(u32 x) { return __uint_as_float(x << 16); }
__device__ __forceinline__ float bfhi(u32 x) { return __uint_as_float(x & 0xFFFF0000u); }
__device__ __forceinline__ void gload16(const u16* g, u16* l) {
  __builtin_amdgcn_global_load_lds(
      (__attribute__((address_space(1))) void*)(g),
      (__attribute__((address_space(3))) void*)(l), 16, 0, 0);
}

// ---------------- weight split+transpose: W f32 [512][512] -> Bt bf16 [512][1024] ----
__global__ __launch_bounds__(256)
void wsplit_kernel(const float* __restrict__ W, u16* __restrict__ Bt) {
  int tid = blockIdx.x * 256 + threadIdx.x;
  int n = tid & 511, k = tid >> 9;
  float a = W[(size_t)k * 512 + n];
  u16 hi = f2bf_rne(a);
  u16 lo = f2bf_rne(a - bf2f(hi));
  int kb = k >> 5, kc = k & 31;
  int slotH = kc >> 3, wi = kc & 7;
  int swzH = (slotH     ^ (n & 7)) << 3;
  int swzL = ((4+slotH) ^ (n & 7)) << 3;
  Bt[(size_t)n * 1024 + kb * 64 + swzH + wi] = hi;
  Bt[(size_t)n * 1024 + kb * 64 + swzL + wi] = lo;
}

// ---------------- projection GEMM: C[M][512] = A_f32[M][512] @ W  (3-term bf16 split)
__global__ __launch_bounds__(256, 2)
void gemm_proj(const float* __restrict__ A, const u16* __restrict__ Bt,
               float* __restrict__ C) {
  __shared__ u16 As[128 * 64];
  __shared__ u16 Bs[128 * 64];
  const int t = threadIdx.x;
  const int w = t >> 6, lane = t & 63;
  const int lhi = lane >> 4, l16 = lane & 15;
  const int row0 = blockIdx.x * 128, col0 = blockIdx.y * 128;
  const int wrow = (w >> 1) * 64, wcol = (w & 1) * 64;

  const u16* gB = Bt + (size_t)(col0 + w * 32 + (lane >> 3)) * 1024 + (lane & 7) * 8;
  u16* lB = &Bs[(w * 32) * 64];

  f32x4 acc[4][4];
  #pragma unroll
  for (int i = 0; i < 4; ++i)
    #pragma unroll
    for (int j = 0; j < 4; ++j) acc[i][j] = (f32x4){0.f, 0.f, 0.f, 0.f};

  for (int kb = 0; kb < 16; ++kb) {
    #pragma unroll
    for (int i = 0; i < 4; ++i)
      gload16(gB + kb * 64 + (size_t)i * 8 * 1024, lB + i * 8 * 64);
    #pragma unroll
    for (int i = 0; i < 4; ++i) {
      int r  = (t >> 3) + 32 * i;
      int c4 = (t & 7) * 4;
      float4 v = *reinterpret_cast<const float4*>(
          &A[(size_t)(row0 + r) * 512 + kb * 32 + c4]);
      ushort4 h4, lo4;
      { u16 h = f2bf_rne(v.x); h4.x = h; lo4.x = f2bf_rne(v.x - bf2f(h)); }
      { u16 h = f2bf_rne(v.y); h4.y = h; lo4.y = f2bf_rne(v.y - bf2f(h)); }
      { u16 h = f2bf_rne(v.z); h4.z = h; lo4.z = f2bf_rne(v.z - bf2f(h)); }
      { u16 h = f2bf_rne(v.w); h4.w = h; lo4.w = f2bf_rne(v.w - bf2f(h)); }
      int slotH = c4 >> 3, wi = c4 & 7;
      int baseH = r * 64 + (((slotH)     ^ (r & 7)) << 3) + wi;
      int baseL = r * 64 + (((4 + slotH) ^ (r & 7)) << 3) + wi;
      *reinterpret_cast<ushort4*>(&As[baseH]) = h4;
      *reinterpret_cast<ushort4*>(&As[baseL]) = lo4;
    }
    __syncthreads();

#define PASS(APART, BPART)                                                      \
    { bf16x8 af[4], bfr[4];                                                     \
      _Pragma("unroll") for (int i = 0; i < 4; ++i) {                           \
        int ra = wrow + i * 16 + l16;                                           \
        af[i] = *reinterpret_cast<const bf16x8*>(                               \
            &As[ra * 64 + ((((APART) + lhi) ^ (ra & 7)) << 3)]); }              \
      _Pragma("unroll") for (int j = 0; j < 4; ++j) {                           \
        int cb = wcol + j * 16 + l16;                                           \
        bfr[j] = *reinterpret_cast<const bf16x8*>(                              \
            &Bs[cb * 64 + ((((BPART) + lhi) ^ (cb & 7)) << 3)]); }              \
      _Pragma("unroll") for (int i = 0; i < 4; ++i)                             \
        _Pragma("unroll") for (int j = 0; j < 4; ++j)                           \
          acc[i][j] = __builtin_amdgcn_mfma_f32_16x16x32_bf16(                  \
              af[i], bfr[j], acc[i][j], 0, 0, 0); }

    PASS(0, 0)
    PASS(0, 4)
    PASS(4, 0)
#undef PASS
    __syncthreads();
  }
  #pragma unroll
  for (int i = 0; i < 4; ++i)
    #pragma unroll
    for (int j = 0; j < 4; ++j)
      #pragma unroll
      for (int r = 0; r < 4; ++r)
        C[(size_t)(row0 + wrow + i * 16 + lhi * 4 + r) * 512
          + col0 + wcol + j * 16 + l16] = acc[i][j][r];
}

// ---------------- generic f32 tiled GEMM (final out GEMM) ---------------------------
template<int BM, int BN, int BK, int TM, int TN>
__global__ __launch_bounds__(256)
void gemm_f32(const float* __restrict__ A, const float* __restrict__ Bm,
              float* __restrict__ C, int M, int N, int K) {
  __shared__ float As[BK][BM + 4];
  __shared__ float Bs[BK][BN + 4];
  const int t = threadIdx.x;
  const int row0 = blockIdx.x * BM;
  const int col0 = blockIdx.y * BN;
  const int NTX = BN / TN;
  const int tx = t % NTX, ty = t / NTX;
  float acc[TM][TN];
  #pragma unroll
  for (int i = 0; i < TM; ++i)
    #pragma unroll
    for (int j = 0; j < TN; ++j) acc[i][j] = 0.f;

  for (int k0 = 0; k0 < K; k0 += BK) {
    #pragma unroll
    for (int e = t * 4; e < BM * BK; e += 1024) {
      int r = e / BK, kk = e % BK;
      float4 v = *reinterpret_cast<const float4*>(&A[(size_t)(row0 + r) * K + k0 + kk]);
      As[kk + 0][r] = v.x; As[kk + 1][r] = v.y; As[kk + 2][r] = v.z; As[kk + 3][r] = v.w;
    }
    #pragma unroll
    for (int e = t * 4; e < BK * BN; e += 1024) {
      int kk = e / BN, c = e % BN;
      *reinterpret_cast<float4*>(&Bs[kk][c]) =
          *reinterpret_cast<const float4*>(&Bm[(size_t)(k0 + kk) * N + col0 + c]);
    }
    __syncthreads();
    #pragma unroll
    for (int k = 0; k < BK; ++k) {
      float a[TM], b[TN];
      #pragma unroll
      for (int i = 0; i < TM; ++i) a[i] = As[k][ty * TM + i];
      #pragma unroll
      for (int j = 0; j < TN; ++j) b[j] = Bs[k][tx * TN + j];
      #pragma unroll
      for (int i = 0; i < TM; ++i)
        #pragma unroll
        for (int j = 0; j < TN; ++j) acc[i][j] += a[i] * b[j];
    }
    __syncthreads();
  }
  #pragma unroll
  for (int i = 0; i < TM; ++i)
    #pragma unroll
    for (int j = 0; j < TN; j += 4) {
      float4 o = make_float4(acc[i][j], acc[i][j+1], acc[i][j+2], acc[i][j+3]);
      *reinterpret_cast<float4*>(&C[(size_t)(row0 + ty * TM + i) * N + col0 + tx * TN + j]) = o;
    }
}

// ---------------- dot + M (f32, exact top-k path) -----------------------------------
__global__ __launch_bounds__(256)
void dot_kernel(const float* __restrict__ qp, const float* __restrict__ kp,
                const int* __restrict__ indx, float* __restrict__ dotM) {
  int tid = blockIdx.x * 256 + threadIdx.x;
  int w = tid >> 6;
  int lane = tid & 63;
  int bh = w >> 11;
  int l = w & 2047;
  size_t boff = (size_t)bh * (L_ * D_);
  float q = qp[boff + (size_t)l * D_ + lane];
  int ls = indx[l];
  float k = kp[boff + (size_t)ls * D_ + lane];
  float p = q * k;
  #pragma unroll
  for (int off = 32; off >= 1; off >>= 1) p += __shfl_xor(p, off, 64);
  if (lane == 0) {
    const float cUL = 40.0f / 2048.0f;
    dotM[(size_t)bh * L_ + l] = p - p * cUL;
  }
}

// ---------------- per-(b,h) top-40 by value, ties -> lower index --------------------
__global__ __launch_bounds__(256)
void topk_kernel(const float* __restrict__ dotM, int* __restrict__ mtop) {
  __shared__ float vals[L_];
  __shared__ float rv[256];
  __shared__ int   ri[256];
  int bh = blockIdx.x, t = threadIdx.x;
  const float* row = dotM + (size_t)bh * L_;
  for (int i = t; i < L_; i += 256) vals[i] = row[i];
  __syncthreads();
  for (int u = 0; u < U_; ++u) {
    float bv = -INFINITY; int bi = 0x7fffffff;
    for (int i = t; i < L_; i += 256) {
      float v = vals[i];
      if (v > bv || (v == bv && i < bi)) { bv = v; bi = i; }
    }
    rv[t] = bv; ri[t] = bi;
    __syncthreads();
    for (int s = 128; s > 0; s >>= 1) {
      if (t < s) {
        float v2 = rv[t + s]; int i2 = ri[t + s];
        if (v2 > rv[t] || (v2 == rv[t] && i2 < ri[t])) { rv[t] = v2; ri[t] = i2; }
      }
      __syncthreads();
    }
    if (t == 0) { mtop[bh * U_ + u] = ri[0]; vals[ri[0]] = -INFINITY; }
    __syncthreads();
  }
}

// ---------------- gather selected q rows -> bf16, x0.125, 48-row padded -------------
__global__ __launch_bounds__(256)
void gather_q_kernel(const float* __restrict__ qp, const int* __restrict__ mtop,
                     u16* __restrict__ qredbf) {
  int tid = blockIdx.x * 256 + threadIdx.x;   // BH*48*64 total
  int s = tid >> 6;        // bh*48 + u
  int d = tid & 63;
  int bh = s / 48;
  int u = s - bh * 48;
  float val = 0.f;
  if (u < U_) {
    int m = mtop[bh * U_ + u];
    val = qp[(size_t)bh * (L_ * D_) + (size_t)m * D_ + d] * 0.125f;
  }
  qredbf[tid] = f2bf_rne(val);
}

// ---------------- kconv: kp f32 [b][l][h][d] -> kbf bf16 [bh][l][d] -----------------
__global__ __launch_bounds__(256)
void kconv_kernel(const float* __restrict__ kp, u16* __restrict__ kbf) {
  int o = (blockIdx.x * 256 + threadIdx.x) * 4;   // over 16M
  int d = o & 63;
  int l = (o >> 6) & 2047;
  int h = (o >> 17) & 7;
  int b = o >> 20;
  float4 v = *reinterpret_cast<const float4*>(
      &kp[((size_t)(b * 2048 + l)) * 512 + h * 64 + d]);
  uint2 wv;
  wv.x = (u32)f2bf_rne(v.x) | ((u32)f2bf_rne(v.y) << 16);
  wv.y = (u32)f2bf_rne(v.z) | ((u32)f2bf_rne(v.w) << 16);
  *reinterpret_cast<uint2*>(&kbf[o]) = wv;
}

// ---------------- vconvT: vp f32 [bh][l][d] -> vbfT bf16 [bh][d][l] -----------------
__global__ __launch_bounds__(256)
void vconvT_kernel(const float* __restrict__ vp, u16* __restrict__ vbfT) {
  __shared__ float tile[64][65];
  const int bh = blockIdx.x;
  const int l0 = blockIdx.y * 64;
  const int t = threadIdx.x;
  #pragma unroll
  for (int e = t * 4; e < 4096; e += 1024) {
    int l = e >> 6, d = e & 63;
    float4 v = *reinterpret_cast<const float4*>(
        &vp[(size_t)bh * 131072 + (size_t)(l0 + l) * 64 + d]);
    tile[l][d] = v.x; tile[l][d+1] = v.y; tile[l][d+2] = v.z; tile[l][d+3] = v.w;
  }
  __syncthreads();
  const int d = t >> 2, lq = t & 3;
  u32 p[8];
  #pragma unroll
  for (int j = 0; j < 8; ++j) {
    int l = lq * 16 + j * 2;
    p[j] = (u32)f2bf_rne(tile[l][d]) | ((u32)f2bf_rne(tile[l + 1][d]) << 16);
  }
  uint4* dst = reinterpret_cast<uint4*>(
      &vbfT[((size_t)bh * 64 + d) * 2048 + l0 + lq * 16]);
  dst[0] = make_uint4(p[0], p[1], p[2], p[3]);
  dst[1] = make_uint4(p[4], p[5], p[6], p[7]);
}

// ---------------- scores via MFMA: S[bh][u][l] bf16, mask fused ---------------------
// grid (BH, 16): N-tile 128 l; block 256 (wave w -> 32-l slice)
__global__ __launch_bounds__(256)
void scores_mfma(const u16* __restrict__ qredbf, const u16* __restrict__ kbf,
                 const int* __restrict__ mtop, u16* __restrict__ S) {
  __shared__ u16 As[48 * 64];
  __shared__ u16 Bs[128 * 64];
  __shared__ int ms[U_];
  const int bh = blockIdx.x;
  const int l0 = blockIdx.y * 128;
  const int t = threadIdx.x, w = t >> 6, lane = t & 63;
  const int lhi = lane >> 4, l16 = lane & 15;

  for (int e = t; e < 384; e += 256) {
    int r = e >> 3, s = e & 7;
    *reinterpret_cast<uint4*>(&As[r * 64 + ((s ^ (r & 7)) << 3)]) =
        *reinterpret_cast<const uint4*>(&qredbf[(size_t)bh * 3072 + e * 8]);
  }
  for (int e = t; e < 1024; e += 256) {
    int r = e >> 3, s = e & 7;
    *reinterpret_cast<uint4*>(&Bs[r * 64 + ((s ^ (r & 7)) << 3)]) =
        *reinterpret_cast<const uint4*>(
            &kbf[(size_t)bh * 131072 + (size_t)(l0 + r) * 64 + s * 8]);
  }
  if (t < U_) ms[t] = mtop[bh * U_ + t];
  __syncthreads();

  f32x4 acc[3][2];
  #pragma unroll
  for (int m = 0; m < 3; ++m)
    #pragma unroll
    for (int n = 0; n < 2; ++n) acc[m][n] = (f32x4){0.f, 0.f, 0.f, 0.f};

  #pragma unroll
  for (int ks = 0; ks < 2; ++ks) {
    bf16x8 a[3], b[2];
    #pragma unroll
    for (int m = 0; m < 3; ++m) {
      int r = m * 16 + l16;
      a[m] = *reinterpret_cast<const bf16x8*>(
          &As[r * 64 + (((ks * 4 + lhi) ^ (r & 7)) << 3)]);
    }
    #pragma unroll
    for (int n = 0; n < 2; ++n) {
      int cb = w * 32 + n * 16 + l16;
      b[n] = *reinterpret_cast<const bf16x8*>(
          &Bs[cb * 64 + (((ks * 4 + lhi) ^ (cb & 7)) << 3)]);
    }
    #pragma unroll
    for (int m = 0; m < 3; ++m)
      #pragma unroll
      for (int n = 0; n < 2; ++n)
        acc[m][n] = __builtin_amdgcn_mfma_f32_16x16x32_bf16(a[m], b[n], acc[m][n], 0, 0, 0);
  }

  #pragma unroll
  for (int m = 0; m < 3; ++m)
    #pragma unroll
    for (int n = 0; n < 2; ++n)
      #pragma unroll
      for (int r = 0; r < 4; ++r) {
        int u = m * 16 + lhi * 4 + r;
        if (u < U_) {
          int l = l0 + w * 32 + n * 16 + l16;
          float val = acc[m][n][r];
          if (l > ms[u]) val = -INFINITY;
          S[((size_t)bh * 48 + u) * 2048 + l] = f2bf_rne(val);
        }
      }
}

// ---------------- row softmax over l, bf16 in-place (S -> P) ------------------------
__global__ __launch_bounds__(256)
void softmax_kernel(u16* __restrict__ S) {
  __shared__ float red[4];
  const int rr = blockIdx.x;            // bh*40 + u
  const int bh = rr / U_;
  const int u = rr - bh * U_;
  const int t = threadIdx.x;
  uint4* rp = reinterpret_cast<uint4*>(&S[((size_t)bh * 48 + u) * 2048]);
  uint4 raw = rp[t];
  float f[8];
  f[0] = bflo(raw.x); f[1] = bfhi(raw.x); f[2] = bflo(raw.y); f[3] = bfhi(raw.y);
  f[4] = bflo(raw.z); f[5] = bfhi(raw.z); f[6] = bflo(raw.w); f[7] = bfhi(raw.w);
  float m = f[0];
  #pragma unroll
  for (int i = 1; i < 8; ++i) m = fmaxf(m, f[i]);
  #pragma unroll
  for (int off = 32; off >= 1; off >>= 1) m = fmaxf(m, __shfl_xor(m, off, 64));
  if ((t & 63) == 0) red[t >> 6] = m;
  __syncthreads();
  m = fmaxf(fmaxf(red[0], red[1]), fmaxf(red[2], red[3]));
  __syncthreads();
  float s = 0.f;
  #pragma unroll
  for (int i = 0; i < 8; ++i) { f[i] = expf(f[i] - m); s += f[i]; }
  #pragma unroll
  for (int off = 32; off >= 1; off >>= 1) s += __shfl_xor(s, off, 64);
  if ((t & 63) == 0) red[t >> 6] = s;
  __syncthreads();
  s = red[0] + red[1] + red[2] + red[3];
  float inv = 1.0f / s;
  uint4 o;
  o.x = (u32)f2bf_rne(f[0] * inv) | ((u32)f2bf_rne(f[1] * inv) << 16);
  o.y = (u32)f2bf_rne(f[2] * inv) | ((u32)f2bf_rne(f[3] * inv) << 16);
  o.z = (u32)f2bf_rne(f[4] * inv) | ((u32)f2bf_rne(f[5] * inv) << 16);
  o.w = (u32)f2bf_rne(f[6] * inv) | ((u32)f2bf_rne(f[7] * inv) << 16);
  rp[t] = o;
}

// ---------------- PV via MFMA, split-K=2: partial[kh][bh][48][64] -------------------
__global__ __launch_bounds__(256)
void pv_mfma(const u16* __restrict__ Pbf, const u16* __restrict__ vbfT,
             float* __restrict__ partial) {
  __shared__ u16 Ps[48 * 128];
  __shared__ u16 Vs[64 * 128];
  const int bh = blockIdx.x, kh = blockIdx.y;
  const int t = threadIdx.x, w = t >> 6, lane = t & 63;
  const int lhi = lane >> 4, l16 = lane & 15;
  f32x4 acc[3];
  #pragma unroll
  for (int m = 0; m < 3; ++m) acc[m] = (f32x4){0.f, 0.f, 0.f, 0.f};

  for (int ch = 0; ch < 8; ++ch) {
    const int lb = kh * 1024 + ch * 128;
    for (int e = t; e < 768; e += 256) {
      int r = e >> 4, s = e & 15;
      int sw = (s & 8) | ((s & 7) ^ (r & 7));
      *reinterpret_cast<uint4*>(&Ps[r * 128 + (sw << 3)]) =
          *reinterpret_cast<const uint4*>(&Pbf[((size_t)bh * 48 + r) * 2048 + lb + s * 8]);
    }
    for (int e = t; e < 1024; e += 256) {
      int r = e >> 4, s = e & 15;
      int sw = (s & 8) | ((s & 7) ^ (r & 7));
      *reinterpret_cast<uint4*>(&Vs[r * 128 + (sw << 3)]) =
          *reinterpret_cast<const uint4*>(&vbfT[((size_t)bh * 64 + r) * 2048 + lb + s * 8]);
    }
    __syncthreads();
    #pragma unroll
    for (int ks = 0; ks < 4; ++ks) {
      bf16x8 b;
      { int cb = w * 16 + l16; int s = ks * 4 + lhi;
        int sw = (s & 8) | ((s & 7) ^ (cb & 7));
        b = *reinterpret_cast<const bf16x8*>(&Vs[cb * 128 + (sw << 3)]); }
      #pragma unroll
      for (int m = 0; m < 3; ++m) {
        int r = m * 16 + l16; int s = ks * 4 + lhi;
        int sw = (s & 8) | ((s & 7) ^ (r & 7));
        bf16x8 a = *reinterpret_cast<const bf16x8*>(&Ps[r * 128 + (sw << 3)]);
        acc[m] = __builtin_amdgcn_mfma_f32_16x16x32_bf16(a, b, acc[m], 0, 0, 0);
      }
    }
    __syncthreads();
  }
  #pragma unroll
  for (int m = 0; m < 3; ++m)
    #pragma unroll
    for (int r = 0; r < 4; ++r) {
      int u = m * 16 + lhi * 4 + r;
      partial[(((size_t)kh * 128 + bh) * 48 + u) * 64 + w * 16 + l16] = acc[m][r];
    }
}

// ---------------- cumsum 2-phase ----------------------------------------------------
__global__ __launch_bounds__(256)
void cumsumA(const float* __restrict__ vp, float* __restrict__ seg32) {
  int bh = blockIdx.x, sg = blockIdx.y;
  int t = threadIdx.x, w = t >> 6, lane = t & 63;
  int g = sg * 4 + w;
  size_t base = (size_t)bh * 131072 + (size_t)g * 32 * 64;
  float s = 0.f;
  for (int i = 0; i < 32; ++i) s += vp[base + i * 64 + lane];
  seg32[((size_t)bh * 64 + g) * 64 + lane] = s;
}
__global__ __launch_bounds__(256)
void cumsumB(const float* __restrict__ vp, const float* __restrict__ seg32,
             float* __restrict__ ctx) {
  int bh = blockIdx.x, sg = blockIdx.y;
  int t = threadIdx.x, w = t >> 6, lane = t & 63;
  int g = sg * 4 + w;
  float run = 0.f;
  for (int s = 0; s < g; ++s) run += seg32[((size_t)bh * 64 + s) * 64 + lane];
  size_t base = (size_t)bh * 131072 + (size_t)g * 32 * 64;
  for (int i = 0; i < 32; ++i) {
    run += vp[base + i * 64 + lane];
    ctx[base + i * 64 + lane] = run;
  }
}

// ---------------- merge partials + scatter into ctx ---------------------------------
__global__ __launch_bounds__(256)
void scatter_kernel(const float* __restrict__ partial, const int* __restrict__ mtop,
                    float* __restrict__ ctx) {
  int tid = blockIdx.x * 256 + threadIdx.x;
  int s = tid >> 6;
  if (s >= BH * U_) return;
  int d = tid & 63;
  int bh = s / U_;
  int u = s - bh * U_;
  float a = partial[(((size_t)bh) * 48 + u) * 64 + d]
          + partial[(((size_t)(128 + bh)) * 48 + u) * 64 + d];
  ctx[(size_t)bh * 131072 + (size_t)mtop[s] * 64 + d] = a;
}

extern "C" void kernel_launch(void* const* d_in, const int* in_sizes, int n_in,
                              void* d_out, int out_size, void* d_ws, size_t ws_size,
                              hipStream_t stream) {
  const float* q_in = (const float*)d_in[0];
  const float* k_in = (const float*)d_in[1];
  const float* v_in = (const float*)d_in[2];
  const float* Wq   = (const float*)d_in[3];
  const float* Wk   = (const float*)d_in[4];
  const float* Wv   = (const float*)d_in[5];
  const float* Wo   = (const float*)d_in[6];
  const int*   indx = (const int*)d_in[7];
  float* out = (float*)d_out;

  float* ws = (float*)d_ws;
  float* qp   = ws;                         // 16,777,216 f (64 MiB)
  float* kp   = ws + 16777216;
  float* vp   = ws + 33554432;
  float* dotM = ws + 50331648;              // 262,144 f — Bt aliases (dead after proj)
  u16*   qredbf = (u16*)(ws + 50593792);    // 393,216 u16
  int*   mtop = (int*)(ws + 50921472);      // 5,120 ints
  u16*   Bt   = (u16*)dotM;
  // qp region reuse (qp f32 dead after gather_q):
  u16*   kbf  = (u16*)qp;                   // 16M u16 (32 MiB)
  u16*   vbfT = (u16*)(qp + 8388608);       // 16M u16 (32 MiB)
  float* ctx  = qp;                         // written by cumsum AFTER kbf/vbfT dead
  // kp region reuse (kp f32 dead after kconv):
  u16*   S       = (u16*)kp;                // 12,582,912 u16 (24 MiB), Pbf in-place
  float* partial = kp + 6291456;            // 786,432 f (3 MiB)
  float* seg32   = kp + 7077888;            // 524,288 f (2 MiB)

  const int M = B_ * L_;                    // 32768

  // projections via 3-term bf16-split MFMA
  wsplit_kernel<<<1024, 256, 0, stream>>>(Wq, Bt);
  gemm_proj<<<dim3(M / 128, 4), 256, 0, stream>>>(q_in, Bt, qp);
  wsplit_kernel<<<1024, 256, 0, stream>>>(Wk, Bt);
  gemm_proj<<<dim3(M / 128, 4), 256, 0, stream>>>(k_in, Bt, kp);
  wsplit_kernel<<<1024, 256, 0, stream>>>(Wv, Bt);
  gemm_proj<<<dim3(M / 128, 4), 256, 0, stream>>>(v_in, Bt, vp);

  // exact f32 top-k path
  dot_kernel<<<(BH * L_) / 4, 256, 0, stream>>>(qp, kp, indx, dotM);
  topk_kernel<<<BH, 256, 0, stream>>>(dotM, mtop);
  gather_q_kernel<<<(BH * 48 * 64) / 256, 256, 0, stream>>>(qp, mtop, qredbf);

  // bf16 operand prep (into dead qp region)
  kconv_kernel<<<16384, 256, 0, stream>>>(kp, kbf);
  vconvT_kernel<<<dim3(BH, 32), 256, 0, stream>>>(vp, vbfT);

  // attention: scores -> softmax -> PV (all MFMA / vectorized)
  scores_mfma<<<dim3(BH, 16), 256, 0, stream>>>(qredbf, kbf, mtop, S);
  softmax_kernel<<<BH * U_, 256, 0, stream>>>(S);
  pv_mfma<<<dim3(BH, 2), 256, 0, stream>>>(S, vbfT, partial);

  // cumsum of v -> ctx (overwrites qp region; kbf/vbfT dead now)
  cumsumA<<<dim3(BH, 16), 256, 0, stream>>>(vp, seg32);
  cumsumB<<<dim3(BH, 16), 256, 0, stream>>>(vp, seg32, ctx);

  // merge partials + scatter
  scatter_kernel<<<(BH * U_ * 64) / 256, 256, 0, stream>>>(partial, mtop, ctx);

  // out = ctx @ Wo
  gemm_f32<128,64,16,8,4><<<dim3(M / 128, 1), 256, 0, stream>>>(ctx, Wo, out, M, 64, HID_);
}

// Round 5
// 526.888 us; speedup vs baseline: 2.8132x; 1.0941x over previous
//
#include <hip/hip_runtime.h>
#include <hip/hip_bf16.h>
#include <math.h>

#define B_   16
#define L_   2048
#define DIN  512
#define HID_ 512
#define H_   8
#define D_   64
#define U_   40
#define BH   (B_*H_)     // 128

typedef unsigned short u16;
typedef unsigned int u32;
typedef unsigned long long u64;
typedef __bf16 bf16x8 __attribute__((ext_vector_type(8)));
typedef float f32x4 __attribute__((ext_vector_type(4)));

__device__ __forceinline__ u16 f2bf(float x) {            // RNE via HW cvt
  __bf16 b = (__bf16)x;
  return __builtin_bit_cast(unsigned short, b);
}
__device__ __forceinline__ float bf2f(u16 h) {
  return __uint_as_float(((unsigned)h) << 16);
}
__device__ __forceinline__ float bflo(u32 x) { return __uint_as_float(x << 16); }
__device__ __forceinline__ float bfhi(u32 x) { return __uint_as_float(x & 0xFFFF0000u); }
__device__ __forceinline__ u32 pk2(float a, float b) {
  return (u32)f2bf(a) | ((u32)f2bf(b) << 16);
}
__device__ __forceinline__ void gload16(const u16* g, u16* l) {
  __builtin_amdgcn_global_load_lds(
      (__attribute__((address_space(1))) void*)(g),
      (__attribute__((address_space(3))) void*)(l), 16, 0, 0);
}

// ---------------- weight split+transpose: W f32 [512][512] -> Bt bf16 [512][1024] ----
__global__ __launch_bounds__(256)
void wsplit_kernel(const float* __restrict__ W, u16* __restrict__ Bt) {
  int tid = blockIdx.x * 256 + threadIdx.x;
  int n = tid & 511, k = tid >> 9;
  float a = W[(size_t)k * 512 + n];
  u16 hi = f2bf(a);
  u16 lo = f2bf(a - bf2f(hi));
  int kb = k >> 5, kc = k & 31;
  int slotH = kc >> 3, wi = kc & 7;
  int swzH = (slotH     ^ (n & 7)) << 3;
  int swzL = ((4+slotH) ^ (n & 7)) << 3;
  Bt[(size_t)n * 1024 + kb * 64 + swzH + wi] = hi;
  Bt[(size_t)n * 1024 + kb * 64 + swzL + wi] = lo;
}

// ---------------- projection GEMM: C[M][512] = A_f32[M][512] @ W  (3-term bf16 split)
__global__ __launch_bounds__(256, 3)
void gemm_proj(const float* __restrict__ A, const u16* __restrict__ Bt,
               float* __restrict__ C) {
  __shared__ u16 As[128 * 64];
  __shared__ u16 Bs[128 * 64];
  const int t = threadIdx.x;
  const int w = t >> 6, lane = t & 63;
  const int lhi = lane >> 4, l16 = lane & 15;
  const int row0 = blockIdx.x * 128, col0 = blockIdx.y * 128;
  const int wrow = (w >> 1) * 64, wcol = (w & 1) * 64;

  const u16* gB = Bt + (size_t)(col0 + w * 32 + (lane >> 3)) * 1024 + (lane & 7) * 8;
  u16* lB = &Bs[(w * 32) * 64];

  f32x4 acc[4][4];
  #pragma unroll
  for (int i = 0; i < 4; ++i)
    #pragma unroll
    for (int j = 0; j < 4; ++j) acc[i][j] = (f32x4){0.f, 0.f, 0.f, 0.f};

  for (int kb = 0; kb < 16; ++kb) {
    #pragma unroll
    for (int i = 0; i < 4; ++i)
      gload16(gB + kb * 64 + (size_t)i * 8 * 1024, lB + i * 8 * 64);
    #pragma unroll
    for (int i = 0; i < 4; ++i) {
      int r  = (t >> 3) + 32 * i;
      int c4 = (t & 7) * 4;
      float4 v = *reinterpret_cast<const float4*>(
          &A[(size_t)(row0 + r) * 512 + kb * 32 + c4]);
      ushort4 h4, lo4;
      { u16 h = f2bf(v.x); h4.x = h; lo4.x = f2bf(v.x - bf2f(h)); }
      { u16 h = f2bf(v.y); h4.y = h; lo4.y = f2bf(v.y - bf2f(h)); }
      { u16 h = f2bf(v.z); h4.z = h; lo4.z = f2bf(v.z - bf2f(h)); }
      { u16 h = f2bf(v.w); h4.w = h; lo4.w = f2bf(v.w - bf2f(h)); }
      int slotH = c4 >> 3, wi = c4 & 7;
      int baseH = r * 64 + (((slotH)     ^ (r & 7)) << 3) + wi;
      int baseL = r * 64 + (((4 + slotH) ^ (r & 7)) << 3) + wi;
      *reinterpret_cast<ushort4*>(&As[baseH]) = h4;
      *reinterpret_cast<ushort4*>(&As[baseL]) = lo4;
    }
    __syncthreads();

#define PASS(APART, BPART)                                                      \
    { bf16x8 af[4], bfr[4];                                                     \
      _Pragma("unroll") for (int i = 0; i < 4; ++i) {                           \
        int ra = wrow + i * 16 + l16;                                           \
        af[i] = *reinterpret_cast<const bf16x8*>(                               \
            &As[ra * 64 + ((((APART) + lhi) ^ (ra & 7)) << 3)]); }              \
      _Pragma("unroll") for (int j = 0; j < 4; ++j) {                           \
        int cb = wcol + j * 16 + l16;                                           \
        bfr[j] = *reinterpret_cast<const bf16x8*>(                              \
            &Bs[cb * 64 + ((((BPART) + lhi) ^ (cb & 7)) << 3)]); }              \
      _Pragma("unroll") for (int i = 0; i < 4; ++i)                             \
        _Pragma("unroll") for (int j = 0; j < 4; ++j)                           \
          acc[i][j] = __builtin_amdgcn_mfma_f32_16x16x32_bf16(                  \
              af[i], bfr[j], acc[i][j], 0, 0, 0); }

    PASS(0, 0)
    PASS(0, 4)
    PASS(4, 0)
#undef PASS
    __syncthreads();
  }
  #pragma unroll
  for (int i = 0; i < 4; ++i)
    #pragma unroll
    for (int j = 0; j < 4; ++j)
      #pragma unroll
      for (int r = 0; r < 4; ++r)
        C[(size_t)(row0 + wrow + i * 16 + lhi * 4 + r) * 512
          + col0 + wcol + j * 16 + l16] = acc[i][j][r];
}

// ---------------- fused dot + top-40 (exact f32, ties -> lower index) ---------------
__global__ __launch_bounds__(256)
void dotk_kernel(const float* __restrict__ qp, const float* __restrict__ kp,
                 const int* __restrict__ indx, int* __restrict__ mtop) {
  __shared__ u64 keys[L_];
  __shared__ u64 wbest[4];
  const int bh = blockIdx.x, t = threadIdx.x;
  const int w = t >> 6, lane = t & 63;
  const size_t boff = (size_t)bh * (L_ * D_);
  const int l0 = w * 512;
  const float cUL = 40.0f / 2048.0f;
  for (int i = 0; i < 512; i += 4) {
    float p[4];
    #pragma unroll
    for (int jj = 0; jj < 4; ++jj) {
      int l = l0 + i + jj;
      int ls = indx[l];
      float qv = qp[boff + (size_t)l * 64 + lane];
      float kv = kp[boff + (size_t)ls * 64 + lane];
      p[jj] = qv * kv;
    }
    #pragma unroll
    for (int off = 32; off >= 1; off >>= 1)
      #pragma unroll
      for (int jj = 0; jj < 4; ++jj) p[jj] += __shfl_xor(p[jj], off, 64);
    if (lane == 0) {
      #pragma unroll
      for (int jj = 0; jj < 4; ++jj) {
        int l = l0 + i + jj;
        float Mv = p[jj] - p[jj] * cUL;
        u32 fb = __float_as_uint(Mv);
        u32 mapped = (fb & 0x80000000u) ? ~fb : (fb | 0x80000000u);
        keys[l] = ((u64)mapped << 32) | (u64)(0xFFFFFFFFu - (u32)l);
      }
    }
  }
  __syncthreads();
  for (int u = 0; u < U_; ++u) {
    u64 best = 0;
    #pragma unroll
    for (int i = 0; i < 8; ++i) {
      u64 v = keys[t + i * 256];
      if (v > best) best = v;
    }
    #pragma unroll
    for (int off = 32; off >= 1; off >>= 1) {
      u64 v = __shfl_xor(best, off, 64);
      if (v > best) best = v;
    }
    if (lane == 0) wbest[w] = best;
    __syncthreads();
    if (t == 0) {
      u64 b = wbest[0];
      if (wbest[1] > b) b = wbest[1];
      if (wbest[2] > b) b = wbest[2];
      if (wbest[3] > b) b = wbest[3];
      int idx = (int)(0xFFFFFFFFu - (u32)b);
      mtop[bh * U_ + u] = idx;
      keys[idx] = 0;
    }
    __syncthreads();
  }
}

// ---------------- gather selected q rows -> bf16, x0.125, 48-row padded -------------
__global__ __launch_bounds__(256)
void gather_q_kernel(const float* __restrict__ qp, const int* __restrict__ mtop,
                     u16* __restrict__ qredbf) {
  int tid = blockIdx.x * 256 + threadIdx.x;   // BH*48*64 total
  int s = tid >> 6;
  int d = tid & 63;
  int bh = s / 48;
  int u = s - bh * 48;
  float val = 0.f;
  if (u < U_) {
    int m = mtop[bh * U_ + u];
    val = qp[(size_t)bh * (L_ * D_) + (size_t)m * D_ + d] * 0.125f;
  }
  qredbf[tid] = f2bf(val);
}

// ---------------- vconvT: vp f32 [bh][l][d] -> vbfT bf16 [bh][d][l] -----------------
__global__ __launch_bounds__(256)
void vconvT_kernel(const float* __restrict__ vp, u16* __restrict__ vbfT) {
  __shared__ float tile[64][65];
  const int bh = blockIdx.x;
  const int l0 = blockIdx.y * 64;
  const int t = threadIdx.x;
  #pragma unroll
  for (int e = t * 4; e < 4096; e += 1024) {
    int l = e >> 6, d = e & 63;
    float4 v = *reinterpret_cast<const float4*>(
        &vp[(size_t)bh * 131072 + (size_t)(l0 + l) * 64 + d]);
    tile[l][d] = v.x; tile[l][d+1] = v.y; tile[l][d+2] = v.z; tile[l][d+3] = v.w;
  }
  __syncthreads();
  const int d = t >> 2, lq = t & 3;
  u32 p[8];
  #pragma unroll
  for (int j = 0; j < 8; ++j) {
    int l = lq * 16 + j * 2;
    p[j] = pk2(tile[l][d], tile[l + 1][d]);
  }
  uint4* dst = reinterpret_cast<uint4*>(
      &vbfT[((size_t)bh * 64 + d) * 2048 + l0 + lq * 16]);
  dst[0] = make_uint4(p[0], p[1], p[2], p[3]);
  dst[1] = make_uint4(p[4], p[5], p[6], p[7]);
}

// ---------------- scores via MFMA: stages K from f32 kp; S bf16, mask fused ---------
__global__ __launch_bounds__(256)
void scores_mfma(const u16* __restrict__ qredbf, const float* __restrict__ kp,
                 const int* __restrict__ mtop, u16* __restrict__ S) {
  __shared__ u16 As[48 * 64];
  __shared__ u16 Bs[128 * 64];
  __shared__ int ms[U_];
  const int bh = blockIdx.x;
  const int l0 = blockIdx.y * 128;
  const int t = threadIdx.x, w = t >> 6, lane = t & 63;
  const int lhi = lane >> 4, l16 = lane & 15;

  for (int e = t; e < 384; e += 256) {
    int r = e >> 3, s = e & 7;
    *reinterpret_cast<uint4*>(&As[r * 64 + ((s ^ (r & 7)) << 3)]) =
        *reinterpret_cast<const uint4*>(&qredbf[(size_t)bh * 3072 + e * 8]);
  }
  #pragma unroll
  for (int ee = 0; ee < 4; ++ee) {
    int e = t + ee * 256;
    int r = e >> 3, s = e & 7;
    const float* src = &kp[(size_t)bh * 131072 + (size_t)(l0 + r) * 64 + s * 8];
    float4 va = *reinterpret_cast<const float4*>(src);
    float4 vb = *reinterpret_cast<const float4*>(src + 4);
    uint4 w4 = make_uint4(pk2(va.x, va.y), pk2(va.z, va.w),
                          pk2(vb.x, vb.y), pk2(vb.z, vb.w));
    *reinterpret_cast<uint4*>(&Bs[r * 64 + ((s ^ (r & 7)) << 3)]) = w4;
  }
  if (t < U_) ms[t] = mtop[bh * U_ + t];
  __syncthreads();

  f32x4 acc[3][2];
  #pragma unroll
  for (int m = 0; m < 3; ++m)
    #pragma unroll
    for (int n = 0; n < 2; ++n) acc[m][n] = (f32x4){0.f, 0.f, 0.f, 0.f};

  #pragma unroll
  for (int ks = 0; ks < 2; ++ks) {
    bf16x8 a[3], b[2];
    #pragma unroll
    for (int m = 0; m < 3; ++m) {
      int r = m * 16 + l16;
      a[m] = *reinterpret_cast<const bf16x8*>(
          &As[r * 64 + (((ks * 4 + lhi) ^ (r & 7)) << 3)]);
    }
    #pragma unroll
    for (int n = 0; n < 2; ++n) {
      int cb = w * 32 + n * 16 + l16;
      b[n] = *reinterpret_cast<const bf16x8*>(
          &Bs[cb * 64 + (((ks * 4 + lhi) ^ (cb & 7)) << 3)]);
    }
    #pragma unroll
    for (int m = 0; m < 3; ++m)
      #pragma unroll
      for (int n = 0; n < 2; ++n)
        acc[m][n] = __builtin_amdgcn_mfma_f32_16x16x32_bf16(a[m], b[n], acc[m][n], 0, 0, 0);
  }

  #pragma unroll
  for (int m = 0; m < 3; ++m)
    #pragma unroll
    for (int n = 0; n < 2; ++n)
      #pragma unroll
      for (int r = 0; r < 4; ++r) {
        int u = m * 16 + lhi * 4 + r;
        if (u < U_) {
          int l = l0 + w * 32 + n * 16 + l16;
          float val = acc[m][n][r];
          if (l > ms[u]) val = -INFINITY;
          S[((size_t)bh * 48 + u) * 2048 + l] = f2bf(val);
        }
      }
}

// ---------------- row softmax over l, bf16 in-place (S -> P) ------------------------
__global__ __launch_bounds__(256)
void softmax_kernel(u16* __restrict__ S) {
  __shared__ float red[4];
  const int rr = blockIdx.x;            // bh*40 + u
  const int bh = rr / U_;
  const int u = rr - bh * U_;
  const int t = threadIdx.x;
  uint4* rp = reinterpret_cast<uint4*>(&S[((size_t)bh * 48 + u) * 2048]);
  uint4 raw = rp[t];
  float f[8];
  f[0] = bflo(raw.x); f[1] = bfhi(raw.x); f[2] = bflo(raw.y); f[3] = bfhi(raw.y);
  f[4] = bflo(raw.z); f[5] = bfhi(raw.z); f[6] = bflo(raw.w); f[7] = bfhi(raw.w);
  float m = f[0];
  #pragma unroll
  for (int i = 1; i < 8; ++i) m = fmaxf(m, f[i]);
  #pragma unroll
  for (int off = 32; off >= 1; off >>= 1) m = fmaxf(m, __shfl_xor(m, off, 64));
  if ((t & 63) == 0) red[t >> 6] = m;
  __syncthreads();
  m = fmaxf(fmaxf(red[0], red[1]), fmaxf(red[2], red[3]));
  __syncthreads();
  float s = 0.f;
  #pragma unroll
  for (int i = 0; i < 8; ++i) { f[i] = expf(f[i] - m); s += f[i]; }
  #pragma unroll
  for (int off = 32; off >= 1; off >>= 1) s += __shfl_xor(s, off, 64);
  if ((t & 63) == 0) red[t >> 6] = s;
  __syncthreads();
  s = red[0] + red[1] + red[2] + red[3];
  float inv = 1.0f / s;
  uint4 o;
  o.x = pk2(f[0] * inv, f[1] * inv);
  o.y = pk2(f[2] * inv, f[3] * inv);
  o.z = pk2(f[4] * inv, f[5] * inv);
  o.w = pk2(f[6] * inv, f[7] * inv);
  rp[t] = o;
}

// ---------------- PV via MFMA, split-K=2: partial[kh][bh][48][64] -------------------
__global__ __launch_bounds__(256)
void pv_mfma(const u16* __restrict__ Pbf, const u16* __restrict__ vbfT,
             float* __restrict__ partial) {
  __shared__ u16 Ps[48 * 128];
  __shared__ u16 Vs[64 * 128];
  const int bh = blockIdx.x, kh = blockIdx.y;
  const int t = threadIdx.x, w = t >> 6, lane = t & 63;
  const int lhi = lane >> 4, l16 = lane & 15;
  f32x4 acc[3];
  #pragma unroll
  for (int m = 0; m < 3; ++m) acc[m] = (f32x4){0.f, 0.f, 0.f, 0.f};

  for (int ch = 0; ch < 8; ++ch) {
    const int lb = kh * 1024 + ch * 128;
    for (int e = t; e < 768; e += 256) {
      int r = e >> 4, s = e & 15;
      int sw = (s & 8) | ((s & 7) ^ (r & 7));
      *reinterpret_cast<uint4*>(&Ps[r * 128 + (sw << 3)]) =
          *reinterpret_cast<const uint4*>(&Pbf[((size_t)bh * 48 + r) * 2048 + lb + s * 8]);
    }
    for (int e = t; e < 1024; e += 256) {
      int r = e >> 4, s = e & 15;
      int sw = (s & 8) | ((s & 7) ^ (r & 7));
      *reinterpret_cast<uint4*>(&Vs[r * 128 + (sw << 3)]) =
          *reinterpret_cast<const uint4*>(&vbfT[((size_t)bh * 64 + r) * 2048 + lb + s * 8]);
    }
    __syncthreads();
    #pragma unroll
    for (int ks = 0; ks < 4; ++ks) {
      bf16x8 b;
      { int cb = w * 16 + l16; int s = ks * 4 + lhi;
        int sw = (s & 8) | ((s & 7) ^ (cb & 7));
        b = *reinterpret_cast<const bf16x8*>(&Vs[cb * 128 + (sw << 3)]); }
      #pragma unroll
      for (int m = 0; m < 3; ++m) {
        int r = m * 16 + l16; int s = ks * 4 + lhi;
        int sw = (s & 8) | ((s & 7) ^ (r & 7));
        bf16x8 a = *reinterpret_cast<const bf16x8*>(&Ps[r * 128 + (sw << 3)]);
        acc[m] = __builtin_amdgcn_mfma_f32_16x16x32_bf16(a, b, acc[m], 0, 0, 0);
      }
    }
    __syncthreads();
  }
  #pragma unroll
  for (int m = 0; m < 3; ++m)
    #pragma unroll
    for (int r = 0; r < 4; ++r) {
      int u = m * 16 + lhi * 4 + r;
      partial[(((size_t)kh * 128 + bh) * 48 + u) * 64 + w * 16 + l16] = acc[m][r];
    }
}

// ---------------- cumsum 2-phase ----------------------------------------------------
__global__ __launch_bounds__(256)
void cumsumA(const float* __restrict__ vp, float* __restrict__ seg32) {
  int bh = blockIdx.x, sg = blockIdx.y;
  int t = threadIdx.x, w = t >> 6, lane = t & 63;
  int g = sg * 4 + w;
  size_t base = (size_t)bh * 131072 + (size_t)g * 32 * 64;
  float s = 0.f;
  for (int i = 0; i < 32; ++i) s += vp[base + i * 64 + lane];
  seg32[((size_t)bh * 64 + g) * 64 + lane] = s;
}
__global__ __launch_bounds__(256)
void cumsumB(const float* __restrict__ vp, const float* __restrict__ seg32,
             float* __restrict__ ctx) {
  int bh = blockIdx.x, sg = blockIdx.y;
  int t = threadIdx.x, w = t >> 6, lane = t & 63;
  int g = sg * 4 + w;
  float run = 0.f;
  for (int s = 0; s < g; ++s) run += seg32[((size_t)bh * 64 + s) * 64 + lane];
  size_t base = (size_t)bh * 131072 + (size_t)g * 32 * 64;
  for (int i = 0; i < 32; ++i) {
    run += vp[base + i * 64 + lane];
    ctx[base + i * 64 + lane] = run;
  }
}

// ---------------- merge partials + scatter into ctx ---------------------------------
__global__ __launch_bounds__(256)
void scatter_kernel(const float* __restrict__ partial, const int* __restrict__ mtop,
                    float* __restrict__ ctx) {
  int tid = blockIdx.x * 256 + threadIdx.x;
  int s = tid >> 6;
  if (s >= BH * U_) return;
  int d = tid & 63;
  int bh = s / U_;
  int u = s - bh * U_;
  float a = partial[(((size_t)bh) * 48 + u) * 64 + d]
          + partial[(((size_t)(128 + bh)) * 48 + u) * 64 + d];
  ctx[(size_t)bh * 131072 + (size_t)mtop[s] * 64 + d] = a;
}

// ---------------- Wo -> bf16, transposed + swizzled: WoT[j][512] --------------------
__global__ __launch_bounds__(256)
void wo_prep(const float* __restrict__ Wo, u16* __restrict__ WoT) {
  int tid = blockIdx.x * 256 + threadIdx.x;   // 32768
  int j = tid >> 9, k = tid & 511;
  float v = Wo[(size_t)k * 64 + j];
  int k0 = k & ~63, ko = k & 63;
  int ks = ko >> 5, kc = ko & 31;
  int slot = (ks * 4 + (kc >> 3)) ^ (j & 7);
  WoT[(size_t)j * 512 + k0 + (slot << 3) + (kc & 7)] = f2bf(v);
}

// ---------------- out GEMM via MFMA (plain bf16): out[M][64] = ctx @ Wo -------------
__global__ __launch_bounds__(256, 6)
void gemm_out(const float* __restrict__ ctx, const u16* __restrict__ WoT,
              float* __restrict__ out) {
  __shared__ u16 As[64 * 64];
  __shared__ u16 Bs[64 * 64];
  const int t = threadIdx.x, w = t >> 6, lane = t & 63;
  const int lhi = lane >> 4, l16 = lane & 15;
  const int row0 = blockIdx.x * 64;
  f32x4 acc[4];
  #pragma unroll
  for (int j = 0; j < 4; ++j) acc[j] = (f32x4){0.f, 0.f, 0.f, 0.f};

  for (int k0 = 0; k0 < 512; k0 += 64) {
    #pragma unroll
    for (int ii = 0; ii < 2; ++ii) {
      int e = t + ii * 256;
      int j = e >> 3, s = e & 7;
      gload16(WoT + (size_t)j * 512 + k0 + s * 8, Bs + (size_t)(w * 64 + ii * 256) * 8);
    }
    #pragma unroll
    for (int ii = 0; ii < 2; ++ii) {
      int e = t + ii * 256;
      int r = e >> 3, s = e & 7;
      const float* src = &ctx[(size_t)(row0 + r) * 512 + k0 + s * 8];
      float4 va = *reinterpret_cast<const float4*>(src);
      float4 vb = *reinterpret_cast<const float4*>(src + 4);
      uint4 w4 = make_uint4(pk2(va.x, va.y), pk2(va.z, va.w),
                            pk2(vb.x, vb.y), pk2(vb.z, vb.w));
      *reinterpret_cast<uint4*>(&As[r * 64 + ((s ^ (r & 7)) << 3)]) = w4;
    }
    __syncthreads();
    #pragma unroll
    for (int ks = 0; ks < 2; ++ks) {
      int r = w * 16 + l16;
      bf16x8 a = *reinterpret_cast<const bf16x8*>(
          &As[r * 64 + (((ks * 4 + lhi) ^ (r & 7)) << 3)]);
      #pragma unroll
      for (int jf = 0; jf < 4; ++jf) {
        int cb = jf * 16 + l16;
        bf16x8 b = *reinterpret_cast<const bf16x8*>(
            &Bs[cb * 64 + (((ks * 4 + lhi) ^ (cb & 7)) << 3)]);
        acc[jf] = __builtin_amdgcn_mfma_f32_16x16x32_bf16(a, b, acc[jf], 0, 0, 0);
      }
    }
    __syncthreads();
  }
  #pragma unroll
  for (int jf = 0; jf < 4; ++jf)
    #pragma unroll
    for (int r = 0; r < 4; ++r)
      out[(size_t)(row0 + w * 16 + lhi * 4 + r) * 64 + jf * 16 + l16] = acc[jf][r];
}

extern "C" void kernel_launch(void* const* d_in, const int* in_sizes, int n_in,
                              void* d_out, int out_size, void* d_ws, size_t ws_size,
                              hipStream_t stream) {
  const float* q_in = (const float*)d_in[0];
  const float* k_in = (const float*)d_in[1];
  const float* v_in = (const float*)d_in[2];
  const float* Wq   = (const float*)d_in[3];
  const float* Wk   = (const float*)d_in[4];
  const float* Wv   = (const float*)d_in[5];
  const float* Wo   = (const float*)d_in[6];
  const int*   indx = (const int*)d_in[7];
  float* out = (float*)d_out;

  float* ws = (float*)d_ws;
  float* qp   = ws;                         // 16,777,216 f (64 MiB)
  float* kp   = ws + 16777216;
  float* vp   = ws + 33554432;
  u16*   Bt   = (u16*)(ws + 50331648);      // 1 MiB split-weight buffer (serial reuse)
  u16*   WoT  = Bt;                         // 64 KiB, after Bt dead
  u16*   qredbf = (u16*)(ws + 50593792);    // 393,216 u16
  int*   mtop = (int*)(ws + 50921472);      // 5,120 ints
  // qp region reuse (qp f32 dead after gather_q):
  u16*   S    = (u16*)qp;                   // 12.6M u16 (24 MiB)
  u16*   vbfT = (u16*)(qp + 8388608);       // 16M u16 (32 MiB)
  float* ctx  = qp;                         // cumsum output (after S/vbfT dead)
  // kp region reuse (kp f32 dead after scores_mfma):
  float* partial = kp;                      // 786,432 f (3 MiB)
  float* seg32   = kp + 1048576;            // 524,288 f (2 MiB)

  const int M = B_ * L_;                    // 32768

  // projections via 3-term bf16-split MFMA
  wsplit_kernel<<<1024, 256, 0, stream>>>(Wq, Bt);
  gemm_proj<<<dim3(M / 128, 4), 256, 0, stream>>>(q_in, Bt, qp);
  wsplit_kernel<<<1024, 256, 0, stream>>>(Wk, Bt);
  gemm_proj<<<dim3(M / 128, 4), 256, 0, stream>>>(k_in, Bt, kp);
  wsplit_kernel<<<1024, 256, 0, stream>>>(Wv, Bt);
  gemm_proj<<<dim3(M / 128, 4), 256, 0, stream>>>(v_in, Bt, vp);

  // exact f32 dot + top-40 (fused)
  dotk_kernel<<<BH, 256, 0, stream>>>(qp, kp, indx, mtop);
  gather_q_kernel<<<(BH * 48 * 64) / 256, 256, 0, stream>>>(qp, mtop, qredbf);

  // bf16 V^T prep (into dead qp region)
  vconvT_kernel<<<dim3(BH, 32), 256, 0, stream>>>(vp, vbfT);

  // attention: scores (stages K from f32 kp) -> softmax -> PV
  scores_mfma<<<dim3(BH, 16), 256, 0, stream>>>(qredbf, kp, mtop, S);
  softmax_kernel<<<BH * U_, 256, 0, stream>>>(S);
  pv_mfma<<<dim3(BH, 2), 256, 0, stream>>>(S, vbfT, partial);

  // cumsum of v -> ctx (overwrites qp region; S/vbfT dead now)
  cumsumA<<<dim3(BH, 16), 256, 0, stream>>>(vp, seg32);
  cumsumB<<<dim3(BH, 16), 256, 0, stream>>>(vp, seg32, ctx);

  // merge partials + scatter
  scatter_kernel<<<(BH * U_ * 64) / 256, 256, 0, stream>>>(partial, mtop, ctx);

  // out = ctx @ Wo via MFMA (plain bf16)
  wo_prep<<<128, 256, 0, stream>>>(Wo, WoT);
  gemm_out<<<M / 64, 256, 0, stream>>>(ctx, WoT, out);
}

// Round 6
// 444.001 us; speedup vs baseline: 3.3384x; 1.1867x over previous
//
#include <hip/hip_runtime.h>
#include <hip/hip_bf16.h>
#include <math.h>

#define B_   16
#define L_   2048
#define DIN  512
#define HID_ 512
#define H_   8
#define D_   64
#define U_   40
#define BH   (B_*H_)     // 128

typedef unsigned short u16;
typedef unsigned int u32;
typedef unsigned long long u64;
typedef __bf16 bf16x8 __attribute__((ext_vector_type(8)));
typedef float f32x4 __attribute__((ext_vector_type(4)));

__device__ __forceinline__ u16 f2bf(float x) {            // RNE via HW cvt
  __bf16 b = (__bf16)x;
  return __builtin_bit_cast(unsigned short, b);
}
__device__ __forceinline__ float bf2f(u16 h) {
  return __uint_as_float(((unsigned)h) << 16);
}
__device__ __forceinline__ float bflo(u32 x) { return __uint_as_float(x << 16); }
__device__ __forceinline__ float bfhi(u32 x) { return __uint_as_float(x & 0xFFFF0000u); }
__device__ __forceinline__ u32 pk2(float a, float b) {
  return (u32)f2bf(a) | ((u32)f2bf(b) << 16);
}
__device__ __forceinline__ void gload16(const u16* g, u16* l) {
  __builtin_amdgcn_global_load_lds(
      (__attribute__((address_space(1))) void*)(g),
      (__attribute__((address_space(3))) void*)(l), 16, 0, 0);
}
__device__ __forceinline__ u64 mkkey(float Mv, int l) {
  u32 fb = __float_as_uint(Mv);
  u32 mapped = (fb & 0x80000000u) ? ~fb : (fb | 0x80000000u);
  return ((u64)mapped << 32) | (u64)(0xFFFFFFFFu - (u32)l);
}

// ---------------- weight split+transpose: W f32 [512][512] -> Bt bf16 [512][1024] ----
__global__ __launch_bounds__(256)
void wsplit_kernel(const float* __restrict__ W, u16* __restrict__ Bt) {
  int tid = blockIdx.x * 256 + threadIdx.x;
  int n = tid & 511, k = tid >> 9;
  float a = W[(size_t)k * 512 + n];
  u16 hi = f2bf(a);
  u16 lo = f2bf(a - bf2f(hi));
  int kb = k >> 5, kc = k & 31;
  int slotH = kc >> 3, wi = kc & 7;
  int swzH = (slotH     ^ (n & 7)) << 3;
  int swzL = ((4+slotH) ^ (n & 7)) << 3;
  Bt[(size_t)n * 1024 + kb * 64 + swzH + wi] = hi;
  Bt[(size_t)n * 1024 + kb * 64 + swzL + wi] = lo;
}

// ---------------- projection GEMM: C[M][512] = A_f32[M][512] @ W  (3-term bf16 split)
__global__ __launch_bounds__(256, 3)
void gemm_proj(const float* __restrict__ A, const u16* __restrict__ Bt,
               float* __restrict__ C) {
  __shared__ u16 As[128 * 64];
  __shared__ u16 Bs[128 * 64];
  const int t = threadIdx.x;
  const int w = t >> 6, lane = t & 63;
  const int lhi = lane >> 4, l16 = lane & 15;
  const int row0 = blockIdx.x * 128, col0 = blockIdx.y * 128;
  const int wrow = (w >> 1) * 64, wcol = (w & 1) * 64;

  const u16* gB = Bt + (size_t)(col0 + w * 32 + (lane >> 3)) * 1024 + (lane & 7) * 8;
  u16* lB = &Bs[(w * 32) * 64];

  f32x4 acc[4][4];
  #pragma unroll
  for (int i = 0; i < 4; ++i)
    #pragma unroll
    for (int j = 0; j < 4; ++j) acc[i][j] = (f32x4){0.f, 0.f, 0.f, 0.f};

  for (int kb = 0; kb < 16; ++kb) {
    #pragma unroll
    for (int i = 0; i < 4; ++i)
      gload16(gB + kb * 64 + (size_t)i * 8 * 1024, lB + i * 8 * 64);
    #pragma unroll
    for (int i = 0; i < 4; ++i) {
      int r  = (t >> 3) + 32 * i;
      int c4 = (t & 7) * 4;
      float4 v = *reinterpret_cast<const float4*>(
          &A[(size_t)(row0 + r) * 512 + kb * 32 + c4]);
      ushort4 h4, lo4;
      { u16 h = f2bf(v.x); h4.x = h; lo4.x = f2bf(v.x - bf2f(h)); }
      { u16 h = f2bf(v.y); h4.y = h; lo4.y = f2bf(v.y - bf2f(h)); }
      { u16 h = f2bf(v.z); h4.z = h; lo4.z = f2bf(v.z - bf2f(h)); }
      { u16 h = f2bf(v.w); h4.w = h; lo4.w = f2bf(v.w - bf2f(h)); }
      int slotH = c4 >> 3, wi = c4 & 7;
      int baseH = r * 64 + (((slotH)     ^ (r & 7)) << 3) + wi;
      int baseL = r * 64 + (((4 + slotH) ^ (r & 7)) << 3) + wi;
      *reinterpret_cast<ushort4*>(&As[baseH]) = h4;
      *reinterpret_cast<ushort4*>(&As[baseL]) = lo4;
    }
    __syncthreads();

#define PASS(APART, BPART)                                                      \
    { bf16x8 af[4], bfr[4];                                                     \
      _Pragma("unroll") for (int i = 0; i < 4; ++i) {                           \
        int ra = wrow + i * 16 + l16;                                           \
        af[i] = *reinterpret_cast<const bf16x8*>(                               \
            &As[ra * 64 + ((((APART) + lhi) ^ (ra & 7)) << 3)]); }              \
      _Pragma("unroll") for (int j = 0; j < 4; ++j) {                           \
        int cb = wcol + j * 16 + l16;                                           \
        bfr[j] = *reinterpret_cast<const bf16x8*>(                              \
            &Bs[cb * 64 + ((((BPART) + lhi) ^ (cb & 7)) << 3)]); }              \
      _Pragma("unroll") for (int i = 0; i < 4; ++i)                             \
        _Pragma("unroll") for (int j = 0; j < 4; ++j)                           \
          acc[i][j] = __builtin_amdgcn_mfma_f32_16x16x32_bf16(                  \
              af[i], bfr[j], acc[i][j], 0, 0, 0); }

    PASS(0, 0)
    PASS(0, 4)
    PASS(4, 0)
#undef PASS
    __syncthreads();
  }
  #pragma unroll
  for (int i = 0; i < 4; ++i)
    #pragma unroll
    for (int j = 0; j < 4; ++j)
      #pragma unroll
      for (int r = 0; r < 4; ++r)
        C[(size_t)(row0 + wrow + i * 16 + lhi * 4 + r) * 512
          + col0 + wcol + j * 16 + l16] = acc[i][j][r];
}

// ---------------- dot + per-chunk top-40 candidates (exact f32) ---------------------
// grid (BH, 8): chunk = 256 l's; wave w computes 64 dots, block selects top-40 keys.
__global__ __launch_bounds__(256)
void dotsel_kernel(const float* __restrict__ qp, const float* __restrict__ kp,
                   const int* __restrict__ indx, u64* __restrict__ cand) {
  __shared__ u64 keys[256];
  __shared__ u64 wmax[4];
  const int bh = blockIdx.x, ch = blockIdx.y;
  const int t = threadIdx.x, w = t >> 6, lane = t & 63;
  const size_t boff = (size_t)bh * 131072;
  const int l0 = ch * 256 + w * 64;
  const float cUL = 40.0f / 2048.0f;

  for (int i = 0; i < 64; i += 4) {
    float p[4];
    #pragma unroll
    for (int jj = 0; jj < 4; ++jj) {
      int l = l0 + i + jj;
      int ls = indx[l];
      p[jj] = qp[boff + (size_t)l * 64 + lane] * kp[boff + (size_t)ls * 64 + lane];
    }
    #pragma unroll
    for (int off = 32; off >= 1; off >>= 1)
      #pragma unroll
      for (int jj = 0; jj < 4; ++jj) p[jj] += __shfl_xor(p[jj], off, 64);
    if (lane == 0) {
      #pragma unroll
      for (int jj = 0; jj < 4; ++jj) {
        float Mv = p[jj] - p[jj] * cUL;
        keys[w * 64 + i + jj] = mkkey(Mv, l0 + i + jj);
      }
    }
  }
  __syncthreads();

  u64 myk = keys[t];
  for (int u = 0; u < U_; ++u) {
    u64 b = myk;
    #pragma unroll
    for (int off = 32; off >= 1; off >>= 1) {
      u64 v = __shfl_xor(b, off, 64);
      if (v > b) b = v;
    }
    if (lane == 0) wmax[w] = b;
    __syncthreads();
    u64 m = wmax[0];
    if (wmax[1] > m) m = wmax[1];
    if (wmax[2] > m) m = wmax[2];
    if (wmax[3] > m) m = wmax[3];
    if (myk == m) myk = 0;              // unique keys: owner clears
    if (t == 0) cand[((size_t)(bh * 8 + ch)) * U_ + u] = m;
    __syncthreads();
  }
}

// ---------------- merge 8x40 candidates -> global top-40 (1 wave per bh) ------------
__global__ __launch_bounds__(64)
void merge_topk(const u64* __restrict__ cand, int* __restrict__ mtop) {
  const int bh = blockIdx.x;
  const int lane = threadIdx.x;
  u64 c0 = cand[(size_t)bh * 320 + 0 * 64 + lane];
  u64 c1 = cand[(size_t)bh * 320 + 1 * 64 + lane];
  u64 c2 = cand[(size_t)bh * 320 + 2 * 64 + lane];
  u64 c3 = cand[(size_t)bh * 320 + 3 * 64 + lane];
  u64 c4 = cand[(size_t)bh * 320 + 4 * 64 + lane];
  for (int u = 0; u < U_; ++u) {
    u64 b = c0;
    if (c1 > b) b = c1;
    if (c2 > b) b = c2;
    if (c3 > b) b = c3;
    if (c4 > b) b = c4;
    #pragma unroll
    for (int off = 32; off >= 1; off >>= 1) {
      u64 v = __shfl_xor(b, off, 64);
      if (v > b) b = v;
    }
    if (c0 == b) c0 = 0;
    if (c1 == b) c1 = 0;
    if (c2 == b) c2 = 0;
    if (c3 == b) c3 = 0;
    if (c4 == b) c4 = 0;
    if (lane == 0) mtop[bh * U_ + u] = (int)(0xFFFFFFFFu - (u32)b);
  }
}

// ---------------- gather selected q rows -> bf16, x0.125, 48-row padded -------------
__global__ __launch_bounds__(256)
void gather_q_kernel(const float* __restrict__ qp, const int* __restrict__ mtop,
                     u16* __restrict__ qredbf) {
  int tid = blockIdx.x * 256 + threadIdx.x;   // BH*48*64 total
  int s = tid >> 6;
  int d = tid & 63;
  int bh = s / 48;
  int u = s - bh * 48;
  float val = 0.f;
  if (u < U_) {
    int m = mtop[bh * U_ + u];
    val = qp[(size_t)bh * (L_ * D_) + (size_t)m * D_ + d] * 0.125f;
  }
  qredbf[tid] = f2bf(val);
}

// ---------------- vconvT: vp f32 [bh][l][d] -> vbfT bf16 [bh][d][l] -----------------
__global__ __launch_bounds__(256)
void vconvT_kernel(const float* __restrict__ vp, u16* __restrict__ vbfT) {
  __shared__ float tile[64][65];
  const int bh = blockIdx.x;
  const int l0 = blockIdx.y * 64;
  const int t = threadIdx.x;
  #pragma unroll
  for (int e = t * 4; e < 4096; e += 1024) {
    int l = e >> 6, d = e & 63;
    float4 v = *reinterpret_cast<const float4*>(
        &vp[(size_t)bh * 131072 + (size_t)(l0 + l) * 64 + d]);
    tile[l][d] = v.x; tile[l][d+1] = v.y; tile[l][d+2] = v.z; tile[l][d+3] = v.w;
  }
  __syncthreads();
  const int d = t >> 2, lq = t & 3;
  u32 p[8];
  #pragma unroll
  for (int j = 0; j < 8; ++j) {
    int l = lq * 16 + j * 2;
    p[j] = pk2(tile[l][d], tile[l + 1][d]);
  }
  uint4* dst = reinterpret_cast<uint4*>(
      &vbfT[((size_t)bh * 64 + d) * 2048 + l0 + lq * 16]);
  dst[0] = make_uint4(p[0], p[1], p[2], p[3]);
  dst[1] = make_uint4(p[4], p[5], p[6], p[7]);
}

// ---------------- scores via MFMA: stages K from f32 kp; S bf16, mask fused ---------
__global__ __launch_bounds__(256)
void scores_mfma(const u16* __restrict__ qredbf, const float* __restrict__ kp,
                 const int* __restrict__ mtop, u16* __restrict__ S) {
  __shared__ u16 As[48 * 64];
  __shared__ u16 Bs[128 * 64];
  __shared__ int ms[U_];
  const int bh = blockIdx.x;
  const int l0 = blockIdx.y * 128;
  const int t = threadIdx.x, w = t >> 6, lane = t & 63;
  const int lhi = lane >> 4, l16 = lane & 15;

  for (int e = t; e < 384; e += 256) {
    int r = e >> 3, s = e & 7;
    *reinterpret_cast<uint4*>(&As[r * 64 + ((s ^ (r & 7)) << 3)]) =
        *reinterpret_cast<const uint4*>(&qredbf[(size_t)bh * 3072 + e * 8]);
  }
  #pragma unroll
  for (int ee = 0; ee < 4; ++ee) {
    int e = t + ee * 256;
    int r = e >> 3, s = e & 7;
    const float* src = &kp[(size_t)bh * 131072 + (size_t)(l0 + r) * 64 + s * 8];
    float4 va = *reinterpret_cast<const float4*>(src);
    float4 vb = *reinterpret_cast<const float4*>(src + 4);
    uint4 w4 = make_uint4(pk2(va.x, va.y), pk2(va.z, va.w),
                          pk2(vb.x, vb.y), pk2(vb.z, vb.w));
    *reinterpret_cast<uint4*>(&Bs[r * 64 + ((s ^ (r & 7)) << 3)]) = w4;
  }
  if (t < U_) ms[t] = mtop[bh * U_ + t];
  __syncthreads();

  f32x4 acc[3][2];
  #pragma unroll
  for (int m = 0; m < 3; ++m)
    #pragma unroll
    for (int n = 0; n < 2; ++n) acc[m][n] = (f32x4){0.f, 0.f, 0.f, 0.f};

  #pragma unroll
  for (int ks = 0; ks < 2; ++ks) {
    bf16x8 a[3], b[2];
    #pragma unroll
    for (int m = 0; m < 3; ++m) {
      int r = m * 16 + l16;
      a[m] = *reinterpret_cast<const bf16x8*>(
          &As[r * 64 + (((ks * 4 + lhi) ^ (r & 7)) << 3)]);
    }
    #pragma unroll
    for (int n = 0; n < 2; ++n) {
      int cb = w * 32 + n * 16 + l16;
      b[n] = *reinterpret_cast<const bf16x8*>(
          &Bs[cb * 64 + (((ks * 4 + lhi) ^ (cb & 7)) << 3)]);
    }
    #pragma unroll
    for (int m = 0; m < 3; ++m)
      #pragma unroll
      for (int n = 0; n < 2; ++n)
        acc[m][n] = __builtin_amdgcn_mfma_f32_16x16x32_bf16(a[m], b[n], acc[m][n], 0, 0, 0);
  }

  #pragma unroll
  for (int m = 0; m < 3; ++m)
    #pragma unroll
    for (int n = 0; n < 2; ++n)
      #pragma unroll
      for (int r = 0; r < 4; ++r) {
        int u = m * 16 + lhi * 4 + r;
        if (u < U_) {
          int l = l0 + w * 32 + n * 16 + l16;
          float val = acc[m][n][r];
          if (l > ms[u]) val = -INFINITY;
          S[((size_t)bh * 48 + u) * 2048 + l] = f2bf(val);
        }
      }
}

// ---------------- row softmax over l, bf16 in-place (S -> P) ------------------------
__global__ __launch_bounds__(256)
void softmax_kernel(u16* __restrict__ S) {
  __shared__ float red[4];
  const int rr = blockIdx.x;            // bh*40 + u
  const int bh = rr / U_;
  const int u = rr - bh * U_;
  const int t = threadIdx.x;
  uint4* rp = reinterpret_cast<uint4*>(&S[((size_t)bh * 48 + u) * 2048]);
  uint4 raw = rp[t];
  float f[8];
  f[0] = bflo(raw.x); f[1] = bfhi(raw.x); f[2] = bflo(raw.y); f[3] = bfhi(raw.y);
  f[4] = bflo(raw.z); f[5] = bfhi(raw.z); f[6] = bflo(raw.w); f[7] = bfhi(raw.w);
  float m = f[0];
  #pragma unroll
  for (int i = 1; i < 8; ++i) m = fmaxf(m, f[i]);
  #pragma unroll
  for (int off = 32; off >= 1; off >>= 1) m = fmaxf(m, __shfl_xor(m, off, 64));
  if ((t & 63) == 0) red[t >> 6] = m;
  __syncthreads();
  m = fmaxf(fmaxf(red[0], red[1]), fmaxf(red[2], red[3]));
  __syncthreads();
  float s = 0.f;
  #pragma unroll
  for (int i = 0; i < 8; ++i) { f[i] = expf(f[i] - m); s += f[i]; }
  #pragma unroll
  for (int off = 32; off >= 1; off >>= 1) s += __shfl_xor(s, off, 64);
  if ((t & 63) == 0) red[t >> 6] = s;
  __syncthreads();
  s = red[0] + red[1] + red[2] + red[3];
  float inv = 1.0f / s;
  uint4 o;
  o.x = pk2(f[0] * inv, f[1] * inv);
  o.y = pk2(f[2] * inv, f[3] * inv);
  o.z = pk2(f[4] * inv, f[5] * inv);
  o.w = pk2(f[6] * inv, f[7] * inv);
  rp[t] = o;
}

// ---------------- PV via MFMA, split-K=2: partial[kh][bh][48][64] -------------------
__global__ __launch_bounds__(256)
void pv_mfma(const u16* __restrict__ Pbf, const u16* __restrict__ vbfT,
             float* __restrict__ partial) {
  __shared__ u16 Ps[48 * 128];
  __shared__ u16 Vs[64 * 128];
  const int bh = blockIdx.x, kh = blockIdx.y;
  const int t = threadIdx.x, w = t >> 6, lane = t & 63;
  const int lhi = lane >> 4, l16 = lane & 15;
  f32x4 acc[3];
  #pragma unroll
  for (int m = 0; m < 3; ++m) acc[m] = (f32x4){0.f, 0.f, 0.f, 0.f};

  for (int ch = 0; ch < 8; ++ch) {
    const int lb = kh * 1024 + ch * 128;
    for (int e = t; e < 768; e += 256) {
      int r = e >> 4, s = e & 15;
      int sw = (s & 8) | ((s & 7) ^ (r & 7));
      *reinterpret_cast<uint4*>(&Ps[r * 128 + (sw << 3)]) =
          *reinterpret_cast<const uint4*>(&Pbf[((size_t)bh * 48 + r) * 2048 + lb + s * 8]);
    }
    for (int e = t; e < 1024; e += 256) {
      int r = e >> 4, s = e & 15;
      int sw = (s & 8) | ((s & 7) ^ (r & 7));
      *reinterpret_cast<uint4*>(&Vs[r * 128 + (sw << 3)]) =
          *reinterpret_cast<const uint4*>(&vbfT[((size_t)bh * 64 + r) * 2048 + lb + s * 8]);
    }
    __syncthreads();
    #pragma unroll
    for (int ks = 0; ks < 4; ++ks) {
      bf16x8 b;
      { int cb = w * 16 + l16; int s = ks * 4 + lhi;
        int sw = (s & 8) | ((s & 7) ^ (cb & 7));
        b = *reinterpret_cast<const bf16x8*>(&Vs[cb * 128 + (sw << 3)]); }
      #pragma unroll
      for (int m = 0; m < 3; ++m) {
        int r = m * 16 + l16; int s = ks * 4 + lhi;
        int sw = (s & 8) | ((s & 7) ^ (r & 7));
        bf16x8 a = *reinterpret_cast<const bf16x8*>(&Ps[r * 128 + (sw << 3)]);
        acc[m] = __builtin_amdgcn_mfma_f32_16x16x32_bf16(a, b, acc[m], 0, 0, 0);
      }
    }
    __syncthreads();
  }
  #pragma unroll
  for (int m = 0; m < 3; ++m)
    #pragma unroll
    for (int r = 0; r < 4; ++r) {
      int u = m * 16 + lhi * 4 + r;
      partial[(((size_t)kh * 128 + bh) * 48 + u) * 64 + w * 16 + l16] = acc[m][r];
    }
}

// ---------------- cumsum 2-phase ----------------------------------------------------
__global__ __launch_bounds__(256)
void cumsumA(const float* __restrict__ vp, float* __restrict__ seg32) {
  int bh = blockIdx.x, sg = blockIdx.y;
  int t = threadIdx.x, w = t >> 6, lane = t & 63;
  int g = sg * 4 + w;
  size_t base = (size_t)bh * 131072 + (size_t)g * 32 * 64;
  float s = 0.f;
  for (int i = 0; i < 32; ++i) s += vp[base + i * 64 + lane];
  seg32[((size_t)bh * 64 + g) * 64 + lane] = s;
}
__global__ __launch_bounds__(256)
void cumsumB(const float* __restrict__ vp, const float* __restrict__ seg32,
             float* __restrict__ ctx) {
  int bh = blockIdx.x, sg = blockIdx.y;
  int t = threadIdx.x, w = t >> 6, lane = t & 63;
  int g = sg * 4 + w;
  float run = 0.f;
  for (int s = 0; s < g; ++s) run += seg32[((size_t)bh * 64 + s) * 64 + lane];
  size_t base = (size_t)bh * 131072 + (size_t)g * 32 * 64;
  for (int i = 0; i < 32; ++i) {
    run += vp[base + i * 64 + lane];
    ctx[base + i * 64 + lane] = run;
  }
}

// ---------------- merge partials + scatter into ctx ---------------------------------
__global__ __launch_bounds__(256)
void scatter_kernel(const float* __restrict__ partial, const int* __restrict__ mtop,
                    float* __restrict__ ctx) {
  int tid = blockIdx.x * 256 + threadIdx.x;
  int s = tid >> 6;
  if (s >= BH * U_) return;
  int d = tid & 63;
  int bh = s / U_;
  int u = s - bh * U_;
  float a = partial[(((size_t)bh) * 48 + u) * 64 + d]
          + partial[(((size_t)(128 + bh)) * 48 + u) * 64 + d];
  ctx[(size_t)bh * 131072 + (size_t)mtop[s] * 64 + d] = a;
}

// ---------------- Wo -> bf16, transposed + swizzled: WoT[j][512] --------------------
__global__ __launch_bounds__(256)
void wo_prep(const float* __restrict__ Wo, u16* __restrict__ WoT) {
  int tid = blockIdx.x * 256 + threadIdx.x;   // 32768
  int j = tid >> 9, k = tid & 511;
  float v = Wo[(size_t)k * 64 + j];
  int k0 = k & ~63, ko = k & 63;
  int ks = ko >> 5, kc = ko & 31;
  int slot = (ks * 4 + (kc >> 3)) ^ (j & 7);
  WoT[(size_t)j * 512 + k0 + (slot << 3) + (kc & 7)] = f2bf(v);
}

// ---------------- out GEMM via MFMA (plain bf16): out[M][64] = ctx @ Wo -------------
__global__ __launch_bounds__(256, 6)
void gemm_out(const float* __restrict__ ctx, const u16* __restrict__ WoT,
              float* __restrict__ out) {
  __shared__ u16 As[64 * 64];
  __shared__ u16 Bs[64 * 64];
  const int t = threadIdx.x, w = t >> 6, lane = t & 63;
  const int lhi = lane >> 4, l16 = lane & 15;
  const int row0 = blockIdx.x * 64;
  f32x4 acc[4];
  #pragma unroll
  for (int j = 0; j < 4; ++j) acc[j] = (f32x4){0.f, 0.f, 0.f, 0.f};

  for (int k0 = 0; k0 < 512; k0 += 64) {
    #pragma unroll
    for (int ii = 0; ii < 2; ++ii) {
      int e = t + ii * 256;
      int j = e >> 3, s = e & 7;
      gload16(WoT + (size_t)j * 512 + k0 + s * 8, Bs + (size_t)(w * 64 + ii * 256) * 8);
    }
    #pragma unroll
    for (int ii = 0; ii < 2; ++ii) {
      int e = t + ii * 256;
      int r = e >> 3, s = e & 7;
      const float* src = &ctx[(size_t)(row0 + r) * 512 + k0 + s * 8];
      float4 va = *reinterpret_cast<const float4*>(src);
      float4 vb = *reinterpret_cast<const float4*>(src + 4);
      uint4 w4 = make_uint4(pk2(va.x, va.y), pk2(va.z, va.w),
                            pk2(vb.x, vb.y), pk2(vb.z, vb.w));
      *reinterpret_cast<uint4*>(&As[r * 64 + ((s ^ (r & 7)) << 3)]) = w4;
    }
    __syncthreads();
    #pragma unroll
    for (int ks = 0; ks < 2; ++ks) {
      int r = w * 16 + l16;
      bf16x8 a = *reinterpret_cast<const bf16x8*>(
          &As[r * 64 + (((ks * 4 + lhi) ^ (r & 7)) << 3)]);
      #pragma unroll
      for (int jf = 0; jf < 4; ++jf) {
        int cb = jf * 16 + l16;
        bf16x8 b = *reinterpret_cast<const bf16x8*>(
            &Bs[cb * 64 + (((ks * 4 + lhi) ^ (cb & 7)) << 3)]);
        acc[jf] = __builtin_amdgcn_mfma_f32_16x16x32_bf16(a, b, acc[jf], 0, 0, 0);
      }
    }
    __syncthreads();
  }
  #pragma unroll
  for (int jf = 0; jf < 4; ++jf)
    #pragma unroll
    for (int r = 0; r < 4; ++r)
      out[(size_t)(row0 + w * 16 + lhi * 4 + r) * 64 + jf * 16 + l16] = acc[jf][r];
}

extern "C" void kernel_launch(void* const* d_in, const int* in_sizes, int n_in,
                              void* d_out, int out_size, void* d_ws, size_t ws_size,
                              hipStream_t stream) {
  const float* q_in = (const float*)d_in[0];
  const float* k_in = (const float*)d_in[1];
  const float* v_in = (const float*)d_in[2];
  const float* Wq   = (const float*)d_in[3];
  const float* Wk   = (const float*)d_in[4];
  const float* Wv   = (const float*)d_in[5];
  const float* Wo   = (const float*)d_in[6];
  const int*   indx = (const int*)d_in[7];
  float* out = (float*)d_out;

  float* ws = (float*)d_ws;
  float* qp   = ws;                         // 16,777,216 f (64 MiB)
  float* kp   = ws + 16777216;
  float* vp   = ws + 33554432;
  u16*   Bt   = (u16*)(ws + 50331648);      // 1 MiB split-weight buffer (serial reuse)
  u64*   cand = (u64*)Bt;                   // 320 KiB — after Bt dead, before WoT
  u16*   WoT  = (u16*)Bt;                   // 64 KiB — after cand dead
  u16*   qredbf = (u16*)(ws + 50593792);    // 393,216 u16
  int*   mtop = (int*)(ws + 50921472);      // 5,120 ints
  // qp region reuse (qp f32 dead after gather_q):
  u16*   S    = (u16*)qp;                   // 12.6M u16 (24 MiB)
  u16*   vbfT = (u16*)(qp + 8388608);       // 16M u16 (32 MiB)
  float* ctx  = qp;                         // cumsum output (after S/vbfT dead)
  // kp region reuse (kp f32 dead after scores_mfma):
  float* partial = kp;                      // 786,432 f (3 MiB)
  float* seg32   = kp + 1048576;            // 524,288 f (2 MiB)

  const int M = B_ * L_;                    // 32768

  // projections via 3-term bf16-split MFMA
  wsplit_kernel<<<1024, 256, 0, stream>>>(Wq, Bt);
  gemm_proj<<<dim3(M / 128, 4), 256, 0, stream>>>(q_in, Bt, qp);
  wsplit_kernel<<<1024, 256, 0, stream>>>(Wk, Bt);
  gemm_proj<<<dim3(M / 128, 4), 256, 0, stream>>>(k_in, Bt, kp);
  wsplit_kernel<<<1024, 256, 0, stream>>>(Wv, Bt);
  gemm_proj<<<dim3(M / 128, 4), 256, 0, stream>>>(v_in, Bt, vp);

  // exact f32 dot + two-level top-40 (Bt dead -> cand aliases it)
  dotsel_kernel<<<dim3(BH, 8), 256, 0, stream>>>(qp, kp, indx, cand);
  merge_topk<<<BH, 64, 0, stream>>>(cand, mtop);
  gather_q_kernel<<<(BH * 48 * 64) / 256, 256, 0, stream>>>(qp, mtop, qredbf);

  // bf16 V^T prep (into dead qp region)
  vconvT_kernel<<<dim3(BH, 32), 256, 0, stream>>>(vp, vbfT);

  // attention: scores (stages K from f32 kp) -> softmax -> PV
  scores_mfma<<<dim3(BH, 16), 256, 0, stream>>>(qredbf, kp, mtop, S);
  softmax_kernel<<<BH * U_, 256, 0, stream>>>(S);
  pv_mfma<<<dim3(BH, 2), 256, 0, stream>>>(S, vbfT, partial);

  // cumsum of v -> ctx (overwrites qp region; S/vbfT dead now)
  cumsumA<<<dim3(BH, 16), 256, 0, stream>>>(vp, seg32);
  cumsumB<<<dim3(BH, 16), 256, 0, stream>>>(vp, seg32, ctx);

  // merge partials + scatter
  scatter_kernel<<<(BH * U_ * 64) / 256, 256, 0, stream>>>(partial, mtop, ctx);

  // out = ctx @ Wo via MFMA (plain bf16)
  wo_prep<<<128, 256, 0, stream>>>(Wo, WoT);
  gemm_out<<<M / 64, 256, 0, stream>>>(ctx, WoT, out);
}

// Round 7
// 374.632 us; speedup vs baseline: 3.9566x; 1.1852x over previous
//
#include <hip/hip_runtime.h>
#include <hip/hip_bf16.h>
#include <math.h>

#define B_   16
#define L_   2048
#define DIN  512
#define HID_ 512
#define H_   8
#define D_   64
#define U_   40
#define BH   (B_*H_)     // 128

typedef unsigned short u16;
typedef unsigned int u32;
typedef unsigned long long u64;
typedef __bf16 bf16x8 __attribute__((ext_vector_type(8)));
typedef float f32x4 __attribute__((ext_vector_type(4)));

__device__ __forceinline__ u16 f2bf(float x) {            // RNE via HW cvt
  __bf16 b = (__bf16)x;
  return __builtin_bit_cast(unsigned short, b);
}
__device__ __forceinline__ float bf2f(u16 h) {
  return __uint_as_float(((unsigned)h) << 16);
}
__device__ __forceinline__ float bflo(u32 x) { return __uint_as_float(x << 16); }
__device__ __forceinline__ float bfhi(u32 x) { return __uint_as_float(x & 0xFFFF0000u); }
__device__ __forceinline__ u32 pk2(float a, float b) {
  return (u32)f2bf(a) | ((u32)f2bf(b) << 16);
}
__device__ __forceinline__ void gload16(const u16* g, u16* l) {
  __builtin_amdgcn_global_load_lds(
      (__attribute__((address_space(1))) void*)(g),
      (__attribute__((address_space(3))) void*)(l), 16, 0, 0);
}
__device__ __forceinline__ u64 mkkey(float Mv, int l) {
  u32 fb = __float_as_uint(Mv);
  u32 mapped = (fb & 0x80000000u) ? ~fb : (fb | 0x80000000u);
  return ((u64)mapped << 32) | (u64)(0xFFFFFFFFu - (u32)l);
}

// ---------------- weight split+transpose: W f32 [512][512] -> Bt bf16 [512][1024] ----
__global__ __launch_bounds__(256)
void wsplit_kernel(const float* __restrict__ W, u16* __restrict__ Bt) {
  int tid = blockIdx.x * 256 + threadIdx.x;
  int n = tid & 511, k = tid >> 9;
  float a = W[(size_t)k * 512 + n];
  u16 hi = f2bf(a);
  u16 lo = f2bf(a - bf2f(hi));
  int kb = k >> 5, kc = k & 31;
  int slotH = kc >> 3, wi = kc & 7;
  int swzH = (slotH     ^ (n & 7)) << 3;
  int swzL = ((4+slotH) ^ (n & 7)) << 3;
  Bt[(size_t)n * 1024 + kb * 64 + swzH + wi] = hi;
  Bt[(size_t)n * 1024 + kb * 64 + swzL + wi] = lo;
}

// ---------------- projection GEMM: C[M][512] = A_f32[M][512] @ W --------------------
// NPASS=3: 3-term bf16 split (exact-ish, for q/k).  NPASS=1: plain bf16 (v).
template<int NPASS>
__global__ __launch_bounds__(256, 4)
void gemm_proj(const float* __restrict__ A, const u16* __restrict__ Bt,
               float* __restrict__ C) {
  __shared__ u16 As[128 * 64];
  __shared__ u16 Bs[128 * 64];
  const int t = threadIdx.x;
  const int w = t >> 6, lane = t & 63;
  const int lhi = lane >> 4, l16 = lane & 15;
  const int row0 = blockIdx.x * 128, col0 = blockIdx.y * 128;
  const int wrow = (w >> 1) * 64, wcol = (w & 1) * 64;

  const u16* gB = Bt + (size_t)(col0 + w * 32 + (lane >> 3)) * 1024 + (lane & 7) * 8;
  u16* lB = &Bs[(w * 32) * 64];

  f32x4 acc[4][4];
  #pragma unroll
  for (int i = 0; i < 4; ++i)
    #pragma unroll
    for (int j = 0; j < 4; ++j) acc[i][j] = (f32x4){0.f, 0.f, 0.f, 0.f};

  for (int kb = 0; kb < 16; ++kb) {
    #pragma unroll
    for (int i = 0; i < 4; ++i)
      gload16(gB + kb * 64 + (size_t)i * 8 * 1024, lB + i * 8 * 64);
    #pragma unroll
    for (int i = 0; i < 4; ++i) {
      int r  = (t >> 3) + 32 * i;
      int c4 = (t & 7) * 4;
      float4 v = *reinterpret_cast<const float4*>(
          &A[(size_t)(row0 + r) * 512 + kb * 32 + c4]);
      ushort4 h4;
      h4.x = f2bf(v.x); h4.y = f2bf(v.y); h4.z = f2bf(v.z); h4.w = f2bf(v.w);
      int slotH = c4 >> 3, wi = c4 & 7;
      int baseH = r * 64 + (((slotH)     ^ (r & 7)) << 3) + wi;
      *reinterpret_cast<ushort4*>(&As[baseH]) = h4;
      if constexpr (NPASS == 3) {
        ushort4 lo4;
        lo4.x = f2bf(v.x - bf2f(h4.x)); lo4.y = f2bf(v.y - bf2f(h4.y));
        lo4.z = f2bf(v.z - bf2f(h4.z)); lo4.w = f2bf(v.w - bf2f(h4.w));
        int baseL = r * 64 + (((4 + slotH) ^ (r & 7)) << 3) + wi;
        *reinterpret_cast<ushort4*>(&As[baseL]) = lo4;
      }
    }
    __syncthreads();

#define PASS(APART, BPART)                                                      \
    { bf16x8 af[4], bfr[4];                                                     \
      _Pragma("unroll") for (int i = 0; i < 4; ++i) {                           \
        int ra = wrow + i * 16 + l16;                                           \
        af[i] = *reinterpret_cast<const bf16x8*>(                               \
            &As[ra * 64 + ((((APART) + lhi) ^ (ra & 7)) << 3)]); }              \
      _Pragma("unroll") for (int j = 0; j < 4; ++j) {                           \
        int cb = wcol + j * 16 + l16;                                           \
        bfr[j] = *reinterpret_cast<const bf16x8*>(                              \
            &Bs[cb * 64 + ((((BPART) + lhi) ^ (cb & 7)) << 3)]); }              \
      _Pragma("unroll") for (int i = 0; i < 4; ++i)                             \
        _Pragma("unroll") for (int j = 0; j < 4; ++j)                           \
          acc[i][j] = __builtin_amdgcn_mfma_f32_16x16x32_bf16(                  \
              af[i], bfr[j], acc[i][j], 0, 0, 0); }

    PASS(0, 0)
    if constexpr (NPASS == 3) {
      PASS(0, 4)
      PASS(4, 0)
    }
#undef PASS
    __syncthreads();
  }
  #pragma unroll
  for (int i = 0; i < 4; ++i)
    #pragma unroll
    for (int j = 0; j < 4; ++j)
      #pragma unroll
      for (int r = 0; r < 4; ++r)
        C[(size_t)(row0 + wrow + i * 16 + lhi * 4 + r) * 512
          + col0 + wcol + j * 16 + l16] = acc[i][j][r];
}

// ---------------- dot + per-chunk top-40 candidates (exact f32) ---------------------
__global__ __launch_bounds__(256)
void dotsel_kernel(const float* __restrict__ qp, const float* __restrict__ kp,
                   const int* __restrict__ indx, u64* __restrict__ cand) {
  __shared__ u64 keys[256];
  __shared__ u64 wmax[4];
  const int bh = blockIdx.x, ch = blockIdx.y;
  const int t = threadIdx.x, w = t >> 6, lane = t & 63;
  const size_t boff = (size_t)bh * 131072;
  const int l0 = ch * 256 + w * 64;
  const float cUL = 40.0f / 2048.0f;

  for (int i = 0; i < 64; i += 4) {
    float p[4];
    #pragma unroll
    for (int jj = 0; jj < 4; ++jj) {
      int l = l0 + i + jj;
      int ls = indx[l];
      p[jj] = qp[boff + (size_t)l * 64 + lane] * kp[boff + (size_t)ls * 64 + lane];
    }
    #pragma unroll
    for (int off = 32; off >= 1; off >>= 1)
      #pragma unroll
      for (int jj = 0; jj < 4; ++jj) p[jj] += __shfl_xor(p[jj], off, 64);
    if (lane == 0) {
      #pragma unroll
      for (int jj = 0; jj < 4; ++jj) {
        float Mv = p[jj] - p[jj] * cUL;
        keys[w * 64 + i + jj] = mkkey(Mv, l0 + i + jj);
      }
    }
  }
  __syncthreads();

  u64 myk = keys[t];
  for (int u = 0; u < U_; ++u) {
    u64 b = myk;
    #pragma unroll
    for (int off = 32; off >= 1; off >>= 1) {
      u64 v = __shfl_xor(b, off, 64);
      if (v > b) b = v;
    }
    if (lane == 0) wmax[w] = b;
    __syncthreads();
    u64 m = wmax[0];
    if (wmax[1] > m) m = wmax[1];
    if (wmax[2] > m) m = wmax[2];
    if (wmax[3] > m) m = wmax[3];
    if (myk == m) myk = 0;              // unique keys: owner clears
    if (t == 0) cand[((size_t)(bh * 8 + ch)) * U_ + u] = m;
    __syncthreads();
  }
}

// ---------------- merge 8x40 candidates -> global top-40 (1 wave per bh) ------------
__global__ __launch_bounds__(64)
void merge_topk(const u64* __restrict__ cand, int* __restrict__ mtop) {
  const int bh = blockIdx.x;
  const int lane = threadIdx.x;
  u64 c0 = cand[(size_t)bh * 320 + 0 * 64 + lane];
  u64 c1 = cand[(size_t)bh * 320 + 1 * 64 + lane];
  u64 c2 = cand[(size_t)bh * 320 + 2 * 64 + lane];
  u64 c3 = cand[(size_t)bh * 320 + 3 * 64 + lane];
  u64 c4 = cand[(size_t)bh * 320 + 4 * 64 + lane];
  for (int u = 0; u < U_; ++u) {
    u64 b = c0;
    if (c1 > b) b = c1;
    if (c2 > b) b = c2;
    if (c3 > b) b = c3;
    if (c4 > b) b = c4;
    #pragma unroll
    for (int off = 32; off >= 1; off >>= 1) {
      u64 v = __shfl_xor(b, off, 64);
      if (v > b) b = v;
    }
    if (c0 == b) c0 = 0;
    if (c1 == b) c1 = 0;
    if (c2 == b) c2 = 0;
    if (c3 == b) c3 = 0;
    if (c4 == b) c4 = 0;
    if (lane == 0) mtop[bh * U_ + u] = (int)(0xFFFFFFFFu - (u32)b);
  }
}

// ---------------- gather selected q rows -> bf16, x0.125, 48-row padded -------------
__global__ __launch_bounds__(256)
void gather_q_kernel(const float* __restrict__ qp, const int* __restrict__ mtop,
                     u16* __restrict__ qredbf) {
  int tid = blockIdx.x * 256 + threadIdx.x;   // BH*48*64 total
  int s = tid >> 6;
  int d = tid & 63;
  int bh = s / 48;
  int u = s - bh * 48;
  float val = 0.f;
  if (u < U_) {
    int m = mtop[bh * U_ + u];
    val = qp[(size_t)bh * (L_ * D_) + (size_t)m * D_ + d] * 0.125f;
  }
  qredbf[tid] = f2bf(val);
}

// ---------------- scores via MFMA: stages K from f32 kp; S bf16, mask fused ---------
__global__ __launch_bounds__(256)
void scores_mfma(const u16* __restrict__ qredbf, const float* __restrict__ kp,
                 const int* __restrict__ mtop, u16* __restrict__ S) {
  __shared__ u16 As[48 * 64];
  __shared__ u16 Bs[128 * 64];
  __shared__ int ms[U_];
  const int bh = blockIdx.x;
  const int l0 = blockIdx.y * 128;
  const int t = threadIdx.x, w = t >> 6, lane = t & 63;
  const int lhi = lane >> 4, l16 = lane & 15;

  for (int e = t; e < 384; e += 256) {
    int r = e >> 3, s = e & 7;
    *reinterpret_cast<uint4*>(&As[r * 64 + ((s ^ (r & 7)) << 3)]) =
        *reinterpret_cast<const uint4*>(&qredbf[(size_t)bh * 3072 + e * 8]);
  }
  #pragma unroll
  for (int ee = 0; ee < 4; ++ee) {
    int e = t + ee * 256;
    int r = e >> 3, s = e & 7;
    const float* src = &kp[(size_t)bh * 131072 + (size_t)(l0 + r) * 64 + s * 8];
    float4 va = *reinterpret_cast<const float4*>(src);
    float4 vb = *reinterpret_cast<const float4*>(src + 4);
    uint4 w4 = make_uint4(pk2(va.x, va.y), pk2(va.z, va.w),
                          pk2(vb.x, vb.y), pk2(vb.z, vb.w));
    *reinterpret_cast<uint4*>(&Bs[r * 64 + ((s ^ (r & 7)) << 3)]) = w4;
  }
  if (t < U_) ms[t] = mtop[bh * U_ + t];
  __syncthreads();

  f32x4 acc[3][2];
  #pragma unroll
  for (int m = 0; m < 3; ++m)
    #pragma unroll
    for (int n = 0; n < 2; ++n) acc[m][n] = (f32x4){0.f, 0.f, 0.f, 0.f};

  #pragma unroll
  for (int ks = 0; ks < 2; ++ks) {
    bf16x8 a[3], b[2];
    #pragma unroll
    for (int m = 0; m < 3; ++m) {
      int r = m * 16 + l16;
      a[m] = *reinterpret_cast<const bf16x8*>(
          &As[r * 64 + (((ks * 4 + lhi) ^ (r & 7)) << 3)]);
    }
    #pragma unroll
    for (int n = 0; n < 2; ++n) {
      int cb = w * 32 + n * 16 + l16;
      b[n] = *reinterpret_cast<const bf16x8*>(
          &Bs[cb * 64 + (((ks * 4 + lhi) ^ (cb & 7)) << 3)]);
    }
    #pragma unroll
    for (int m = 0; m < 3; ++m)
      #pragma unroll
      for (int n = 0; n < 2; ++n)
        acc[m][n] = __builtin_amdgcn_mfma_f32_16x16x32_bf16(a[m], b[n], acc[m][n], 0, 0, 0);
  }

  #pragma unroll
  for (int m = 0; m < 3; ++m)
    #pragma unroll
    for (int n = 0; n < 2; ++n)
      #pragma unroll
      for (int r = 0; r < 4; ++r) {
        int u = m * 16 + lhi * 4 + r;
        if (u < U_) {
          int l = l0 + w * 32 + n * 16 + l16;
          float val = acc[m][n][r];
          if (l > ms[u]) val = -INFINITY;
          S[((size_t)bh * 48 + u) * 2048 + l] = f2bf(val);
        }
      }
}

// ---------------- row softmax over l, bf16 in-place (S -> P) ------------------------
__global__ __launch_bounds__(256)
void softmax_kernel(u16* __restrict__ S) {
  __shared__ float red[4];
  const int rr = blockIdx.x;            // bh*40 + u
  const int bh = rr / U_;
  const int u = rr - bh * U_;
  const int t = threadIdx.x;
  uint4* rp = reinterpret_cast<uint4*>(&S[((size_t)bh * 48 + u) * 2048]);
  uint4 raw = rp[t];
  float f[8];
  f[0] = bflo(raw.x); f[1] = bfhi(raw.x); f[2] = bflo(raw.y); f[3] = bfhi(raw.y);
  f[4] = bflo(raw.z); f[5] = bfhi(raw.z); f[6] = bflo(raw.w); f[7] = bfhi(raw.w);
  float m = f[0];
  #pragma unroll
  for (int i = 1; i < 8; ++i) m = fmaxf(m, f[i]);
  #pragma unroll
  for (int off = 32; off >= 1; off >>= 1) m = fmaxf(m, __shfl_xor(m, off, 64));
  if ((t & 63) == 0) red[t >> 6] = m;
  __syncthreads();
  m = fmaxf(fmaxf(red[0], red[1]), fmaxf(red[2], red[3]));
  __syncthreads();
  float s = 0.f;
  #pragma unroll
  for (int i = 0; i < 8; ++i) { f[i] = expf(f[i] - m); s += f[i]; }
  #pragma unroll
  for (int off = 32; off >= 1; off >>= 1) s += __shfl_xor(s, off, 64);
  if ((t & 63) == 0) red[t >> 6] = s;
  __syncthreads();
  s = red[0] + red[1] + red[2] + red[3];
  float inv = 1.0f / s;
  uint4 o;
  o.x = pk2(f[0] * inv, f[1] * inv);
  o.y = pk2(f[2] * inv, f[3] * inv);
  o.z = pk2(f[4] * inv, f[5] * inv);
  o.w = pk2(f[6] * inv, f[7] * inv);
  rp[t] = o;
}

// ---------------- PV via MFMA, split-K=8, V transposed+converted in-kernel ----------
// grid (BH, 8): kh-chunk of 256 l's; partial[kh][bh][48][64]
__global__ __launch_bounds__(256)
void pv_mfma(const u16* __restrict__ Pbf, const float* __restrict__ vp,
             float* __restrict__ partial) {
  __shared__ u16 Ps[48 * 128];
  __shared__ u16 Vs[64 * 128];
  const int bh = blockIdx.x, kh = blockIdx.y;
  const int t = threadIdx.x, w = t >> 6, lane = t & 63;
  const int lhi = lane >> 4, l16 = lane & 15;
  const size_t vbase = (size_t)bh * 131072;
  f32x4 acc[3];
  #pragma unroll
  for (int m = 0; m < 3; ++m) acc[m] = (f32x4){0.f, 0.f, 0.f, 0.f};

  for (int ch = 0; ch < 2; ++ch) {
    const int lb = kh * 256 + ch * 128;
    // stage P[48][128] (swizzled)
    for (int e = t; e < 768; e += 256) {
      int r = e >> 4, s = e & 15;
      int sw = (s & 8) | ((s & 7) ^ (r & 7));
      *reinterpret_cast<uint4*>(&Ps[r * 128 + (sw << 3)]) =
          *reinterpret_cast<const uint4*>(&Pbf[((size_t)bh * 48 + r) * 2048 + lb + s * 8]);
    }
    // stage V transposed: lane owns d=lane; wave w covers l-locals [w*32, w*32+32)
    #pragma unroll
    for (int j = 0; j < 16; ++j) {
      int ll = w * 32 + 2 * j;
      float a = vp[vbase + (size_t)(lb + ll) * 64 + lane];
      float b = vp[vbase + (size_t)(lb + ll + 1) * 64 + lane];
      u32 pk = pk2(a, b);
      int s = ll >> 3;
      int sw = (s & 8) | ((s & 7) ^ (lane & 7));
      *reinterpret_cast<u32*>(&Vs[lane * 128 + (sw << 3) + (ll & 7)]) = pk;
    }
    __syncthreads();
    #pragma unroll
    for (int ks = 0; ks < 4; ++ks) {
      bf16x8 b;
      { int cb = w * 16 + l16; int s = ks * 4 + lhi;
        int sw = (s & 8) | ((s & 7) ^ (cb & 7));
        b = *reinterpret_cast<const bf16x8*>(&Vs[cb * 128 + (sw << 3)]); }
      #pragma unroll
      for (int m = 0; m < 3; ++m) {
        int r = m * 16 + l16; int s = ks * 4 + lhi;
        int sw = (s & 8) | ((s & 7) ^ (r & 7));
        bf16x8 a = *reinterpret_cast<const bf16x8*>(&Ps[r * 128 + (sw << 3)]);
        acc[m] = __builtin_amdgcn_mfma_f32_16x16x32_bf16(a, b, acc[m], 0, 0, 0);
      }
    }
    __syncthreads();
  }
  #pragma unroll
  for (int m = 0; m < 3; ++m)
    #pragma unroll
    for (int r = 0; r < 4; ++r) {
      int u = m * 16 + lhi * 4 + r;
      partial[(((size_t)kh * 128 + bh) * 48 + u) * 64 + w * 16 + l16] = acc[m][r];
    }
}

// ---------------- cumsum 2-phase ----------------------------------------------------
__global__ __launch_bounds__(256)
void cumsumA(const float* __restrict__ vp, float* __restrict__ seg32) {
  int bh = blockIdx.x, sg = blockIdx.y;
  int t = threadIdx.x, w = t >> 6, lane = t & 63;
  int g = sg * 4 + w;
  size_t base = (size_t)bh * 131072 + (size_t)g * 32 * 64;
  float s = 0.f;
  for (int i = 0; i < 32; ++i) s += vp[base + i * 64 + lane];
  seg32[((size_t)bh * 64 + g) * 64 + lane] = s;
}
__global__ __launch_bounds__(256)
void cumsumB(const float* __restrict__ vp, const float* __restrict__ seg32,
             float* __restrict__ ctx) {
  int bh = blockIdx.x, sg = blockIdx.y;
  int t = threadIdx.x, w = t >> 6, lane = t & 63;
  int g = sg * 4 + w;
  float run = 0.f;
  for (int s = 0; s < g; ++s) run += seg32[((size_t)bh * 64 + s) * 64 + lane];
  size_t base = (size_t)bh * 131072 + (size_t)g * 32 * 64;
  for (int i = 0; i < 32; ++i) {
    run += vp[base + i * 64 + lane];
    ctx[base + i * 64 + lane] = run;
  }
}

// ---------------- merge 8 partials + scatter into ctx -------------------------------
__global__ __launch_bounds__(256)
void scatter_kernel(const float* __restrict__ partial, const int* __restrict__ mtop,
                    float* __restrict__ ctx) {
  int tid = blockIdx.x * 256 + threadIdx.x;
  int s = tid >> 6;
  if (s >= BH * U_) return;
  int d = tid & 63;
  int bh = s / U_;
  int u = s - bh * U_;
  float a = 0.f;
  #pragma unroll
  for (int c = 0; c < 8; ++c)
    a += partial[(((size_t)(c * 128 + bh)) * 48 + u) * 64 + d];
  ctx[(size_t)bh * 131072 + (size_t)mtop[s] * 64 + d] = a;
}

// ---------------- Wo -> bf16, transposed + swizzled: WoT[j][512] --------------------
__global__ __launch_bounds__(256)
void wo_prep(const float* __restrict__ Wo, u16* __restrict__ WoT) {
  int tid = blockIdx.x * 256 + threadIdx.x;   // 32768
  int j = tid >> 9, k = tid & 511;
  float v = Wo[(size_t)k * 64 + j];
  int k0 = k & ~63, ko = k & 63;
  int ks = ko >> 5, kc = ko & 31;
  int slot = (ks * 4 + (kc >> 3)) ^ (j & 7);
  WoT[(size_t)j * 512 + k0 + (slot << 3) + (kc & 7)] = f2bf(v);
}

// ---------------- out GEMM via MFMA (plain bf16): out[M][64] = ctx @ Wo -------------
__global__ __launch_bounds__(256, 6)
void gemm_out(const float* __restrict__ ctx, const u16* __restrict__ WoT,
              float* __restrict__ out) {
  __shared__ u16 As[64 * 64];
  __shared__ u16 Bs[64 * 64];
  const int t = threadIdx.x, w = t >> 6, lane = t & 63;
  const int lhi = lane >> 4, l16 = lane & 15;
  const int row0 = blockIdx.x * 64;
  f32x4 acc[4];
  #pragma unroll
  for (int j = 0; j < 4; ++j) acc[j] = (f32x4){0.f, 0.f, 0.f, 0.f};

  for (int k0 = 0; k0 < 512; k0 += 64) {
    #pragma unroll
    for (int ii = 0; ii < 2; ++ii) {
      int e = t + ii * 256;
      int j = e >> 3, s = e & 7;
      gload16(WoT + (size_t)j * 512 + k0 + s * 8, Bs + (size_t)(w * 64 + ii * 256) * 8);
    }
    #pragma unroll
    for (int ii = 0; ii < 2; ++ii) {
      int e = t + ii * 256;
      int r = e >> 3, s = e & 7;
      const float* src = &ctx[(size_t)(row0 + r) * 512 + k0 + s * 8];
      float4 va = *reinterpret_cast<const float4*>(src);
      float4 vb = *reinterpret_cast<const float4*>(src + 4);
      uint4 w4 = make_uint4(pk2(va.x, va.y), pk2(va.z, va.w),
                            pk2(vb.x, vb.y), pk2(vb.z, vb.w));
      *reinterpret_cast<uint4*>(&As[r * 64 + ((s ^ (r & 7)) << 3)]) = w4;
    }
    __syncthreads();
    #pragma unroll
    for (int ks = 0; ks < 2; ++ks) {
      int r = w * 16 + l16;
      bf16x8 a = *reinterpret_cast<const bf16x8*>(
          &As[r * 64 + (((ks * 4 + lhi) ^ (r & 7)) << 3)]);
      #pragma unroll
      for (int jf = 0; jf < 4; ++jf) {
        int cb = jf * 16 + l16;
        bf16x8 b = *reinterpret_cast<const bf16x8*>(
            &Bs[cb * 64 + (((ks * 4 + lhi) ^ (cb & 7)) << 3)]);
        acc[jf] = __builtin_amdgcn_mfma_f32_16x16x32_bf16(a, b, acc[jf], 0, 0, 0);
      }
    }
    __syncthreads();
  }
  #pragma unroll
  for (int jf = 0; jf < 4; ++jf)
    #pragma unroll
    for (int r = 0; r < 4; ++r)
      out[(size_t)(row0 + w * 16 + lhi * 4 + r) * 64 + jf * 16 + l16] = acc[jf][r];
}

extern "C" void kernel_launch(void* const* d_in, const int* in_sizes, int n_in,
                              void* d_out, int out_size, void* d_ws, size_t ws_size,
                              hipStream_t stream) {
  const float* q_in = (const float*)d_in[0];
  const float* k_in = (const float*)d_in[1];
  const float* v_in = (const float*)d_in[2];
  const float* Wq   = (const float*)d_in[3];
  const float* Wk   = (const float*)d_in[4];
  const float* Wv   = (const float*)d_in[5];
  const float* Wo   = (const float*)d_in[6];
  const int*   indx = (const int*)d_in[7];
  float* out = (float*)d_out;

  float* ws = (float*)d_ws;
  float* qp   = ws;                         // 16,777,216 f (64 MiB)
  float* kp   = ws + 16777216;
  float* vp   = ws + 33554432;
  u16*   Bt   = (u16*)(ws + 50331648);      // 1 MiB split-weight buffer (serial reuse)
  u64*   cand = (u64*)Bt;                   // 320 KiB — after Bt dead, before WoT
  u16*   WoT  = (u16*)Bt;                   // 64 KiB — after cand dead
  u16*   qredbf = (u16*)(ws + 50593792);    // 393,216 u16
  int*   mtop = (int*)(ws + 50921472);      // 5,120 ints
  // qp region reuse (qp f32 dead after gather_q):
  u16*   S    = (u16*)qp;                   // 12.6M u16 (24 MiB)
  float* ctx  = qp;                         // cumsum output (after S dead)
  // kp region reuse (kp f32 dead after scores_mfma):
  float* partial = kp;                      // 3,145,728 f (12 MiB)
  float* seg32   = kp + 3145728;            // 524,288 f (2 MiB)

  const int M = B_ * L_;                    // 32768

  // projections: q/k exact 3-term split, v plain bf16
  wsplit_kernel<<<1024, 256, 0, stream>>>(Wq, Bt);
  gemm_proj<3><<<dim3(M / 128, 4), 256, 0, stream>>>(q_in, Bt, qp);
  wsplit_kernel<<<1024, 256, 0, stream>>>(Wk, Bt);
  gemm_proj<3><<<dim3(M / 128, 4), 256, 0, stream>>>(k_in, Bt, kp);
  wsplit_kernel<<<1024, 256, 0, stream>>>(Wv, Bt);
  gemm_proj<1><<<dim3(M / 128, 4), 256, 0, stream>>>(v_in, Bt, vp);

  // exact f32 dot + two-level top-40 (Bt dead -> cand aliases it)
  dotsel_kernel<<<dim3(BH, 8), 256, 0, stream>>>(qp, kp, indx, cand);
  merge_topk<<<BH, 64, 0, stream>>>(cand, mtop);
  gather_q_kernel<<<(BH * 48 * 64) / 256, 256, 0, stream>>>(qp, mtop, qredbf);

  // attention: scores (stages K from f32 kp) -> softmax -> PV (stages V from f32 vp)
  scores_mfma<<<dim3(BH, 16), 256, 0, stream>>>(qredbf, kp, mtop, S);
  softmax_kernel<<<BH * U_, 256, 0, stream>>>(S);
  pv_mfma<<<dim3(BH, 8), 256, 0, stream>>>(S, vp, partial);

  // cumsum of v -> ctx (overwrites qp region; S dead now)
  cumsumA<<<dim3(BH, 16), 256, 0, stream>>>(vp, seg32);
  cumsumB<<<dim3(BH, 16), 256, 0, stream>>>(vp, seg32, ctx);

  // merge partials + scatter
  scatter_kernel<<<(BH * U_ * 64) / 256, 256, 0, stream>>>(partial, mtop, ctx);

  // out = ctx @ Wo via MFMA (plain bf16)
  wo_prep<<<128, 256, 0, stream>>>(Wo, WoT);
  gemm_out<<<M / 64, 256, 0, stream>>>(ctx, WoT, out);
}

// Round 8
// 364.623 us; speedup vs baseline: 4.0652x; 1.0274x over previous
//
#include <hip/hip_runtime.h>
#include <hip/hip_bf16.h>
#include <math.h>

#define B_   16
#define L_   2048
#define DIN  512
#define HID_ 512
#define H_   8
#define D_   64
#define U_   40
#define BH   (B_*H_)     // 128

typedef unsigned short u16;
typedef unsigned int u32;
typedef unsigned long long u64;
typedef __bf16 bf16x8 __attribute__((ext_vector_type(8)));
typedef float f32x4 __attribute__((ext_vector_type(4)));

__device__ __forceinline__ u16 f2bf(float x) {            // RNE via HW cvt
  __bf16 b = (__bf16)x;
  return __builtin_bit_cast(unsigned short, b);
}
__device__ __forceinline__ float bf2f(u16 h) {
  return __uint_as_float(((unsigned)h) << 16);
}
__device__ __forceinline__ float bflo(u32 x) { return __uint_as_float(x << 16); }
__device__ __forceinline__ float bfhi(u32 x) { return __uint_as_float(x & 0xFFFF0000u); }
__device__ __forceinline__ u32 pk2(float a, float b) {
  return (u32)f2bf(a) | ((u32)f2bf(b) << 16);
}
__device__ __forceinline__ void gload16(const u16* g, u16* l) {
  __builtin_amdgcn_global_load_lds(
      (__attribute__((address_space(1))) void*)(g),
      (__attribute__((address_space(3))) void*)(l), 16, 0, 0);
}
__device__ __forceinline__ u64 mkkey(float Mv, int l) {
  u32 fb = __float_as_uint(Mv);
  u32 mapped = (fb & 0x80000000u) ? ~fb : (fb | 0x80000000u);
  return ((u64)mapped << 32) | (u64)(0xFFFFFFFFu - (u32)l);
}

// ---------------- weight split+transpose: W f32 [512][512] -> Bt bf16 [512][1024] ----
__global__ __launch_bounds__(256)
void wsplit_kernel(const float* __restrict__ W, u16* __restrict__ Bt) {
  int tid = blockIdx.x * 256 + threadIdx.x;
  int n = tid & 511, k = tid >> 9;
  float a = W[(size_t)k * 512 + n];
  u16 hi = f2bf(a);
  u16 lo = f2bf(a - bf2f(hi));
  int kb = k >> 5, kc = k & 31;
  int slotH = kc >> 3, wi = kc & 7;
  int swzH = (slotH     ^ (n & 7)) << 3;
  int swzL = ((4+slotH) ^ (n & 7)) << 3;
  Bt[(size_t)n * 1024 + kb * 64 + swzH + wi] = hi;
  Bt[(size_t)n * 1024 + kb * 64 + swzL + wi] = lo;
}

// ---------------- projection GEMM: C[M][512] = A_f32[M][512] @ W --------------------
// NPASS=3: 3-term bf16 split (exact-ish, for q/k).  NPASS=1: plain bf16 (v).
// Fragment-reuse inner loop: 16 ds_read_b128 per wave per kb (was 24).
template<int NPASS>
__global__ __launch_bounds__(256, 4)
void gemm_proj(const float* __restrict__ A, const u16* __restrict__ Bt,
               float* __restrict__ C) {
  __shared__ u16 As[128 * 64];
  __shared__ u16 Bs[128 * 64];
  const int t = threadIdx.x;
  const int w = t >> 6, lane = t & 63;
  const int lhi = lane >> 4, l16 = lane & 15;
  const int row0 = blockIdx.x * 128, col0 = blockIdx.y * 128;
  const int wrow = (w >> 1) * 64, wcol = (w & 1) * 64;

  const u16* gB = Bt + (size_t)(col0 + w * 32 + (lane >> 3)) * 1024 + (lane & 7) * 8;
  u16* lB = &Bs[(w * 32) * 64];

  f32x4 acc[4][4];
  #pragma unroll
  for (int i = 0; i < 4; ++i)
    #pragma unroll
    for (int j = 0; j < 4; ++j) acc[i][j] = (f32x4){0.f, 0.f, 0.f, 0.f};

  for (int kb = 0; kb < 16; ++kb) {
    #pragma unroll
    for (int i = 0; i < 4; ++i)
      gload16(gB + kb * 64 + (size_t)i * 8 * 1024, lB + i * 8 * 64);
    #pragma unroll
    for (int i = 0; i < 4; ++i) {
      int r  = (t >> 3) + 32 * i;
      int c4 = (t & 7) * 4;
      float4 v = *reinterpret_cast<const float4*>(
          &A[(size_t)(row0 + r) * 512 + kb * 32 + c4]);
      ushort4 h4;
      h4.x = f2bf(v.x); h4.y = f2bf(v.y); h4.z = f2bf(v.z); h4.w = f2bf(v.w);
      int slotH = c4 >> 3, wi = c4 & 7;
      int baseH = r * 64 + (((slotH)     ^ (r & 7)) << 3) + wi;
      *reinterpret_cast<ushort4*>(&As[baseH]) = h4;
      if constexpr (NPASS == 3) {
        ushort4 lo4;
        lo4.x = f2bf(v.x - bf2f(h4.x)); lo4.y = f2bf(v.y - bf2f(h4.y));
        lo4.z = f2bf(v.z - bf2f(h4.z)); lo4.w = f2bf(v.w - bf2f(h4.w));
        int baseL = r * 64 + (((4 + slotH) ^ (r & 7)) << 3) + wi;
        *reinterpret_cast<ushort4*>(&As[baseL]) = lo4;
      }
    }
    __syncthreads();

    // B fragments once (hi + lo)
    bf16x8 bfH[4], bfL[4];
    #pragma unroll
    for (int j = 0; j < 4; ++j) {
      int cb = wcol + j * 16 + l16;
      bfH[j] = *reinterpret_cast<const bf16x8*>(
          &Bs[cb * 64 + ((lhi ^ (cb & 7)) << 3)]);
      if constexpr (NPASS == 3)
        bfL[j] = *reinterpret_cast<const bf16x8*>(
            &Bs[cb * 64 + (((4 + lhi) ^ (cb & 7)) << 3)]);
    }
    #pragma unroll
    for (int i = 0; i < 4; ++i) {
      int ra = wrow + i * 16 + l16;
      bf16x8 aH = *reinterpret_cast<const bf16x8*>(
          &As[ra * 64 + ((lhi ^ (ra & 7)) << 3)]);
      #pragma unroll
      for (int j = 0; j < 4; ++j)
        acc[i][j] = __builtin_amdgcn_mfma_f32_16x16x32_bf16(aH, bfH[j], acc[i][j], 0, 0, 0);
      if constexpr (NPASS == 3) {
        bf16x8 aL = *reinterpret_cast<const bf16x8*>(
            &As[ra * 64 + (((4 + lhi) ^ (ra & 7)) << 3)]);
        #pragma unroll
        for (int j = 0; j < 4; ++j)
          acc[i][j] = __builtin_amdgcn_mfma_f32_16x16x32_bf16(aH, bfL[j], acc[i][j], 0, 0, 0);
        #pragma unroll
        for (int j = 0; j < 4; ++j)
          acc[i][j] = __builtin_amdgcn_mfma_f32_16x16x32_bf16(aL, bfH[j], acc[i][j], 0, 0, 0);
      }
    }
    __syncthreads();
  }
  #pragma unroll
  for (int i = 0; i < 4; ++i)
    #pragma unroll
    for (int j = 0; j < 4; ++j)
      #pragma unroll
      for (int r = 0; r < 4; ++r)
        C[(size_t)(row0 + wrow + i * 16 + lhi * 4 + r) * 512
          + col0 + wcol + j * 16 + l16] = acc[i][j][r];
}

// ---------------- dot + per-chunk top-40 candidates (exact f32) ---------------------
// grid (BH, 8). Lane layout: li = lane>>4 (l within group of 4), dq = lane&15
// (float4 d-quarter). Dot = 4-FMA chain + 4 intra-16 DPP shuffles.
__global__ __launch_bounds__(256)
void dotsel_kernel(const float* __restrict__ qp, const float* __restrict__ kp,
                   const int* __restrict__ indx, u64* __restrict__ cand) {
  __shared__ u64 keys[256];
  __shared__ u64 wmax[2][4];
  const int bh = blockIdx.x, ch = blockIdx.y;
  const int t = threadIdx.x, w = t >> 6, lane = t & 63;
  const size_t boff = (size_t)bh * 131072;
  const int l0 = ch * 256 + w * 64;
  const float cUL = 40.0f / 2048.0f;
  const int li = lane >> 4;
  const int dq = lane & 15;

  #pragma unroll 4
  for (int i = 0; i < 16; ++i) {
    int l = l0 + i * 4 + li;
    int ls = indx[l];
    float4 q4 = *reinterpret_cast<const float4*>(&qp[boff + (size_t)l * 64 + dq * 4]);
    float4 k4 = *reinterpret_cast<const float4*>(&kp[boff + (size_t)ls * 64 + dq * 4]);
    float p = q4.x * k4.x + q4.y * k4.y + q4.z * k4.z + q4.w * k4.w;
    p += __shfl_xor(p, 1, 64);
    p += __shfl_xor(p, 2, 64);
    p += __shfl_xor(p, 4, 64);
    p += __shfl_xor(p, 8, 64);
    if (dq == 0) {
      float Mv = p - p * cUL;
      keys[w * 64 + i * 4 + li] = mkkey(Mv, l);
    }
  }
  __syncthreads();

  u64 myk = keys[t];
  for (int u = 0; u < U_; ++u) {
    u64 b = myk;
    #pragma unroll
    for (int off = 32; off >= 1; off >>= 1) {
      u64 v = __shfl_xor(b, off, 64);
      if (v > b) b = v;
    }
    if (lane == 0) wmax[u & 1][w] = b;
    __syncthreads();
    const u64* wm = wmax[u & 1];
    u64 m = wm[0];
    if (wm[1] > m) m = wm[1];
    if (wm[2] > m) m = wm[2];
    if (wm[3] > m) m = wm[3];
    if (myk == m) myk = 0;              // unique keys: owner clears
    if (t == 0) cand[((size_t)(bh * 8 + ch)) * U_ + u] = m;
  }
}

// ---------------- merge 8x40 candidates -> global top-40 (1 wave per bh) ------------
__global__ __launch_bounds__(64)
void merge_topk(const u64* __restrict__ cand, int* __restrict__ mtop) {
  const int bh = blockIdx.x;
  const int lane = threadIdx.x;
  u64 c0 = cand[(size_t)bh * 320 + 0 * 64 + lane];
  u64 c1 = cand[(size_t)bh * 320 + 1 * 64 + lane];
  u64 c2 = cand[(size_t)bh * 320 + 2 * 64 + lane];
  u64 c3 = cand[(size_t)bh * 320 + 3 * 64 + lane];
  u64 c4 = cand[(size_t)bh * 320 + 4 * 64 + lane];
  for (int u = 0; u < U_; ++u) {
    u64 b = c0;
    if (c1 > b) b = c1;
    if (c2 > b) b = c2;
    if (c3 > b) b = c3;
    if (c4 > b) b = c4;
    #pragma unroll
    for (int off = 32; off >= 1; off >>= 1) {
      u64 v = __shfl_xor(b, off, 64);
      if (v > b) b = v;
    }
    if (c0 == b) c0 = 0;
    if (c1 == b) c1 = 0;
    if (c2 == b) c2 = 0;
    if (c3 == b) c3 = 0;
    if (c4 == b) c4 = 0;
    if (lane == 0) mtop[bh * U_ + u] = (int)(0xFFFFFFFFu - (u32)b);
  }
}

// ---------------- gather selected q rows -> bf16, x0.125, 48-row padded -------------
__global__ __launch_bounds__(256)
void gather_q_kernel(const float* __restrict__ qp, const int* __restrict__ mtop,
                     u16* __restrict__ qredbf) {
  int tid = blockIdx.x * 256 + threadIdx.x;   // BH*48*64 total
  int s = tid >> 6;
  int d = tid & 63;
  int bh = s / 48;
  int u = s - bh * 48;
  float val = 0.f;
  if (u < U_) {
    int m = mtop[bh * U_ + u];
    val = qp[(size_t)bh * (L_ * D_) + (size_t)m * D_ + d] * 0.125f;
  }
  qredbf[tid] = f2bf(val);
}

// ---------------- scores via MFMA: stages K from f32 kp; S bf16, mask fused ---------
__global__ __launch_bounds__(256)
void scores_mfma(const u16* __restrict__ qredbf, const float* __restrict__ kp,
                 const int* __restrict__ mtop, u16* __restrict__ S) {
  __shared__ u16 As[48 * 64];
  __shared__ u16 Bs[128 * 64];
  __shared__ int ms[U_];
  const int bh = blockIdx.x;
  const int l0 = blockIdx.y * 128;
  const int t = threadIdx.x, w = t >> 6, lane = t & 63;
  const int lhi = lane >> 4, l16 = lane & 15;

  for (int e = t; e < 384; e += 256) {
    int r = e >> 3, s = e & 7;
    *reinterpret_cast<uint4*>(&As[r * 64 + ((s ^ (r & 7)) << 3)]) =
        *reinterpret_cast<const uint4*>(&qredbf[(size_t)bh * 3072 + e * 8]);
  }
  #pragma unroll
  for (int ee = 0; ee < 4; ++ee) {
    int e = t + ee * 256;
    int r = e >> 3, s = e & 7;
    const float* src = &kp[(size_t)bh * 131072 + (size_t)(l0 + r) * 64 + s * 8];
    float4 va = *reinterpret_cast<const float4*>(src);
    float4 vb = *reinterpret_cast<const float4*>(src + 4);
    uint4 w4 = make_uint4(pk2(va.x, va.y), pk2(va.z, va.w),
                          pk2(vb.x, vb.y), pk2(vb.z, vb.w));
    *reinterpret_cast<uint4*>(&Bs[r * 64 + ((s ^ (r & 7)) << 3)]) = w4;
  }
  if (t < U_) ms[t] = mtop[bh * U_ + t];
  __syncthreads();

  f32x4 acc[3][2];
  #pragma unroll
  for (int m = 0; m < 3; ++m)
    #pragma unroll
    for (int n = 0; n < 2; ++n) acc[m][n] = (f32x4){0.f, 0.f, 0.f, 0.f};

  #pragma unroll
  for (int ks = 0; ks < 2; ++ks) {
    bf16x8 a[3], b[2];
    #pragma unroll
    for (int m = 0; m < 3; ++m) {
      int r = m * 16 + l16;
      a[m] = *reinterpret_cast<const bf16x8*>(
          &As[r * 64 + (((ks * 4 + lhi) ^ (r & 7)) << 3)]);
    }
    #pragma unroll
    for (int n = 0; n < 2; ++n) {
      int cb = w * 32 + n * 16 + l16;
      b[n] = *reinterpret_cast<const bf16x8*>(
          &Bs[cb * 64 + (((ks * 4 + lhi) ^ (cb & 7)) << 3)]);
    }
    #pragma unroll
    for (int m = 0; m < 3; ++m)
      #pragma unroll
      for (int n = 0; n < 2; ++n)
        acc[m][n] = __builtin_amdgcn_mfma_f32_16x16x32_bf16(a[m], b[n], acc[m][n], 0, 0, 0);
  }

  #pragma unroll
  for (int m = 0; m < 3; ++m)
    #pragma unroll
    for (int n = 0; n < 2; ++n)
      #pragma unroll
      for (int r = 0; r < 4; ++r) {
        int u = m * 16 + lhi * 4 + r;
        if (u < U_) {
          int l = l0 + w * 32 + n * 16 + l16;
          float val = acc[m][n][r];
          if (l > ms[u]) val = -INFINITY;
          S[((size_t)bh * 48 + u) * 2048 + l] = f2bf(val);
        }
      }
}

// ---------------- row softmax over l, bf16 in-place (S -> P) ------------------------
__global__ __launch_bounds__(256)
void softmax_kernel(u16* __restrict__ S) {
  __shared__ float red[4];
  const int rr = blockIdx.x;            // bh*40 + u
  const int bh = rr / U_;
  const int u = rr - bh * U_;
  const int t = threadIdx.x;
  uint4* rp = reinterpret_cast<uint4*>(&S[((size_t)bh * 48 + u) * 2048]);
  uint4 raw = rp[t];
  float f[8];
  f[0] = bflo(raw.x); f[1] = bfhi(raw.x); f[2] = bflo(raw.y); f[3] = bfhi(raw.y);
  f[4] = bflo(raw.z); f[5] = bfhi(raw.z); f[6] = bflo(raw.w); f[7] = bfhi(raw.w);
  float m = f[0];
  #pragma unroll
  for (int i = 1; i < 8; ++i) m = fmaxf(m, f[i]);
  #pragma unroll
  for (int off = 32; off >= 1; off >>= 1) m = fmaxf(m, __shfl_xor(m, off, 64));
  if ((t & 63) == 0) red[t >> 6] = m;
  __syncthreads();
  m = fmaxf(fmaxf(red[0], red[1]), fmaxf(red[2], red[3]));
  __syncthreads();
  float s = 0.f;
  #pragma unroll
  for (int i = 0; i < 8; ++i) { f[i] = expf(f[i] - m); s += f[i]; }
  #pragma unroll
  for (int off = 32; off >= 1; off >>= 1) s += __shfl_xor(s, off, 64);
  if ((t & 63) == 0) red[t >> 6] = s;
  __syncthreads();
  s = red[0] + red[1] + red[2] + red[3];
  float inv = 1.0f / s;
  uint4 o;
  o.x = pk2(f[0] * inv, f[1] * inv);
  o.y = pk2(f[2] * inv, f[3] * inv);
  o.z = pk2(f[4] * inv, f[5] * inv);
  o.w = pk2(f[6] * inv, f[7] * inv);
  rp[t] = o;
}

// ---------------- PV via MFMA, split-K=8, V transposed+converted in-kernel ----------
__global__ __launch_bounds__(256)
void pv_mfma(const u16* __restrict__ Pbf, const float* __restrict__ vp,
             float* __restrict__ partial) {
  __shared__ u16 Ps[48 * 128];
  __shared__ u16 Vs[64 * 128];
  const int bh = blockIdx.x, kh = blockIdx.y;
  const int t = threadIdx.x, w = t >> 6, lane = t & 63;
  const int lhi = lane >> 4, l16 = lane & 15;
  const size_t vbase = (size_t)bh * 131072;
  f32x4 acc[3];
  #pragma unroll
  for (int m = 0; m < 3; ++m) acc[m] = (f32x4){0.f, 0.f, 0.f, 0.f};

  for (int ch = 0; ch < 2; ++ch) {
    const int lb = kh * 256 + ch * 128;
    for (int e = t; e < 768; e += 256) {
      int r = e >> 4, s = e & 15;
      int sw = (s & 8) | ((s & 7) ^ (r & 7));
      *reinterpret_cast<uint4*>(&Ps[r * 128 + (sw << 3)]) =
          *reinterpret_cast<const uint4*>(&Pbf[((size_t)bh * 48 + r) * 2048 + lb + s * 8]);
    }
    #pragma unroll
    for (int j = 0; j < 16; ++j) {
      int ll = w * 32 + 2 * j;
      float a = vp[vbase + (size_t)(lb + ll) * 64 + lane];
      float b = vp[vbase + (size_t)(lb + ll + 1) * 64 + lane];
      u32 pk = pk2(a, b);
      int s = ll >> 3;
      int sw = (s & 8) | ((s & 7) ^ (lane & 7));
      *reinterpret_cast<u32*>(&Vs[lane * 128 + (sw << 3) + (ll & 7)]) = pk;
    }
    __syncthreads();
    #pragma unroll
    for (int ks = 0; ks < 4; ++ks) {
      bf16x8 b;
      { int cb = w * 16 + l16; int s = ks * 4 + lhi;
        int sw = (s & 8) | ((s & 7) ^ (cb & 7));
        b = *reinterpret_cast<const bf16x8*>(&Vs[cb * 128 + (sw << 3)]); }
      #pragma unroll
      for (int m = 0; m < 3; ++m) {
        int r = m * 16 + l16; int s = ks * 4 + lhi;
        int sw = (s & 8) | ((s & 7) ^ (r & 7));
        bf16x8 a = *reinterpret_cast<const bf16x8*>(&Ps[r * 128 + (sw << 3)]);
        acc[m] = __builtin_amdgcn_mfma_f32_16x16x32_bf16(a, b, acc[m], 0, 0, 0);
      }
    }
    __syncthreads();
  }
  #pragma unroll
  for (int m = 0; m < 3; ++m)
    #pragma unroll
    for (int r = 0; r < 4; ++r) {
      int u = m * 16 + lhi * 4 + r;
      partial[(((size_t)kh * 128 + bh) * 48 + u) * 64 + w * 16 + l16] = acc[m][r];
    }
}

// ---------------- cumsum 2-phase ----------------------------------------------------
__global__ __launch_bounds__(256)
void cumsumA(const float* __restrict__ vp, float* __restrict__ seg32) {
  int bh = blockIdx.x, sg = blockIdx.y;
  int t = threadIdx.x, w = t >> 6, lane = t & 63;
  int g = sg * 4 + w;
  size_t base = (size_t)bh * 131072 + (size_t)g * 32 * 64;
  float s = 0.f;
  for (int i = 0; i < 32; ++i) s += vp[base + i * 64 + lane];
  seg32[((size_t)bh * 64 + g) * 64 + lane] = s;
}
__global__ __launch_bounds__(256)
void cumsumB(const float* __restrict__ vp, const float* __restrict__ seg32,
             float* __restrict__ ctx) {
  int bh = blockIdx.x, sg = blockIdx.y;
  int t = threadIdx.x, w = t >> 6, lane = t & 63;
  int g = sg * 4 + w;
  float run = 0.f;
  for (int s = 0; s < g; ++s) run += seg32[((size_t)bh * 64 + s) * 64 + lane];
  size_t base = (size_t)bh * 131072 + (size_t)g * 32 * 64;
  for (int i = 0; i < 32; ++i) {
    run += vp[base + i * 64 + lane];
    ctx[base + i * 64 + lane] = run;
  }
}

// ---------------- merge 8 partials + scatter into ctx -------------------------------
__global__ __launch_bounds__(256)
void scatter_kernel(const float* __restrict__ partial, const int* __restrict__ mtop,
                    float* __restrict__ ctx) {
  int tid = blockIdx.x * 256 + threadIdx.x;
  int s = tid >> 6;
  if (s >= BH * U_) return;
  int d = tid & 63;
  int bh = s / U_;
  int u = s - bh * U_;
  float a = 0.f;
  #pragma unroll
  for (int c = 0; c < 8; ++c)
    a += partial[(((size_t)(c * 128 + bh)) * 48 + u) * 64 + d];
  ctx[(size_t)bh * 131072 + (size_t)mtop[s] * 64 + d] = a;
}

// ---------------- Wo -> bf16, transposed + swizzled: WoT[j][512] --------------------
__global__ __launch_bounds__(256)
void wo_prep(const float* __restrict__ Wo, u16* __restrict__ WoT) {
  int tid = blockIdx.x * 256 + threadIdx.x;   // 32768
  int j = tid >> 9, k = tid & 511;
  float v = Wo[(size_t)k * 64 + j];
  int k0 = k & ~63, ko = k & 63;
  int ks = ko >> 5, kc = ko & 31;
  int slot = (ks * 4 + (kc >> 3)) ^ (j & 7);
  WoT[(size_t)j * 512 + k0 + (slot << 3) + (kc & 7)] = f2bf(v);
}

// ---------------- out GEMM via MFMA (plain bf16): out[M][64] = ctx @ Wo -------------
__global__ __launch_bounds__(256, 6)
void gemm_out(const float* __restrict__ ctx, const u16* __restrict__ WoT,
              float* __restrict__ out) {
  __shared__ u16 As[64 * 64];
  __shared__ u16 Bs[64 * 64];
  const int t = threadIdx.x, w = t >> 6, lane = t & 63;
  const int lhi = lane >> 4, l16 = lane & 15;
  const int row0 = blockIdx.x * 64;
  f32x4 acc[4];
  #pragma unroll
  for (int j = 0; j < 4; ++j) acc[j] = (f32x4){0.f, 0.f, 0.f, 0.f};

  for (int k0 = 0; k0 < 512; k0 += 64) {
    #pragma unroll
    for (int ii = 0; ii < 2; ++ii) {
      int e = t + ii * 256;
      int j = e >> 3, s = e & 7;
      gload16(WoT + (size_t)j * 512 + k0 + s * 8, Bs + (size_t)(w * 64 + ii * 256) * 8);
    }
    #pragma unroll
    for (int ii = 0; ii < 2; ++ii) {
      int e = t + ii * 256;
      int r = e >> 3, s = e & 7;
      const float* src = &ctx[(size_t)(row0 + r) * 512 + k0 + s * 8];
      float4 va = *reinterpret_cast<const float4*>(src);
      float4 vb = *reinterpret_cast<const float4*>(src + 4);
      uint4 w4 = make_uint4(pk2(va.x, va.y), pk2(va.z, va.w),
                            pk2(vb.x, vb.y), pk2(vb.z, vb.w));
      *reinterpret_cast<uint4*>(&As[r * 64 + ((s ^ (r & 7)) << 3)]) = w4;
    }
    __syncthreads();
    #pragma unroll
    for (int ks = 0; ks < 2; ++ks) {
      int r = w * 16 + l16;
      bf16x8 a = *reinterpret_cast<const bf16x8*>(
          &As[r * 64 + (((ks * 4 + lhi) ^ (r & 7)) << 3)]);
      #pragma unroll
      for (int jf = 0; jf < 4; ++jf) {
        int cb = jf * 16 + l16;
        bf16x8 b = *reinterpret_cast<const bf16x8*>(
            &Bs[cb * 64 + (((ks * 4 + lhi) ^ (cb & 7)) << 3)]);
        acc[jf] = __builtin_amdgcn_mfma_f32_16x16x32_bf16(a, b, acc[jf], 0, 0, 0);
      }
    }
    __syncthreads();
  }
  #pragma unroll
  for (int jf = 0; jf < 4; ++jf)
    #pragma unroll
    for (int r = 0; r < 4; ++r)
      out[(size_t)(row0 + w * 16 + lhi * 4 + r) * 64 + jf * 16 + l16] = acc[jf][r];
}

extern "C" void kernel_launch(void* const* d_in, const int* in_sizes, int n_in,
                              void* d_out, int out_size, void* d_ws, size_t ws_size,
                              hipStream_t stream) {
  const float* q_in = (const float*)d_in[0];
  const float* k_in = (const float*)d_in[1];
  const float* v_in = (const float*)d_in[2];
  const float* Wq   = (const float*)d_in[3];
  const float* Wk   = (const float*)d_in[4];
  const float* Wv   = (const float*)d_in[5];
  const float* Wo   = (const float*)d_in[6];
  const int*   indx = (const int*)d_in[7];
  float* out = (float*)d_out;

  float* ws = (float*)d_ws;
  float* qp   = ws;                         // 16,777,216 f (64 MiB)
  float* kp   = ws + 16777216;
  float* vp   = ws + 33554432;
  u16*   Bt   = (u16*)(ws + 50331648);      // 1 MiB split-weight buffer (serial reuse)
  u64*   cand = (u64*)Bt;                   // 320 KiB — after Bt dead, before WoT
  u16*   WoT  = (u16*)Bt;                   // 64 KiB — after cand dead
  u16*   qredbf = (u16*)(ws + 50593792);    // 393,216 u16
  int*   mtop = (int*)(ws + 50921472);      // 5,120 ints
  // qp region reuse (qp f32 dead after gather_q):
  u16*   S    = (u16*)qp;                   // 12.6M u16 (24 MiB)
  float* ctx  = qp;                         // cumsum output (after S dead)
  // kp region reuse (kp f32 dead after scores_mfma):
  float* partial = kp;                      // 3,145,728 f (12 MiB)
  float* seg32   = kp + 3145728;            // 524,288 f (2 MiB)

  const int M = B_ * L_;                    // 32768

  // projections: q/k exact 3-term split, v plain bf16
  wsplit_kernel<<<1024, 256, 0, stream>>>(Wq, Bt);
  gemm_proj<3><<<dim3(M / 128, 4), 256, 0, stream>>>(q_in, Bt, qp);
  wsplit_kernel<<<1024, 256, 0, stream>>>(Wk, Bt);
  gemm_proj<3><<<dim3(M / 128, 4), 256, 0, stream>>>(k_in, Bt, kp);
  wsplit_kernel<<<1024, 256, 0, stream>>>(Wv, Bt);
  gemm_proj<1><<<dim3(M / 128, 4), 256, 0, stream>>>(v_in, Bt, vp);

  // exact f32 dot + two-level top-40 (Bt dead -> cand aliases it)
  dotsel_kernel<<<dim3(BH, 8), 256, 0, stream>>>(qp, kp, indx, cand);
  merge_topk<<<BH, 64, 0, stream>>>(cand, mtop);
  gather_q_kernel<<<(BH * 48 * 64) / 256, 256, 0, stream>>>(qp, mtop, qredbf);

  // attention: scores (stages K from f32 kp) -> softmax -> PV (stages V from f32 vp)
  scores_mfma<<<dim3(BH, 16), 256, 0, stream>>>(qredbf, kp, mtop, S);
  softmax_kernel<<<BH * U_, 256, 0, stream>>>(S);
  pv_mfma<<<dim3(BH, 8), 256, 0, stream>>>(S, vp, partial);

  // cumsum of v -> ctx (overwrites qp region; S dead now)
  cumsumA<<<dim3(BH, 16), 256, 0, stream>>>(vp, seg32);
  cumsumB<<<dim3(BH, 16), 256, 0, stream>>>(vp, seg32, ctx);

  // merge partials + scatter
  scatter_kernel<<<(BH * U_ * 64) / 256, 256, 0, stream>>>(partial, mtop, ctx);

  // out = ctx @ Wo via MFMA (plain bf16)
  wo_prep<<<128, 256, 0, stream>>>(Wo, WoT);
  gemm_out<<<M / 64, 256, 0, stream>>>(ctx, WoT, out);
}